// Round 16
// baseline (801.947 us; speedup 1.0000x reference)
//
#include <hip/hip_runtime.h>
#include <math.h>

#define Bb 32
#define Nn 128
#define Kk 48
#define Ff 256
#define Gg 50
#define Tt 3

typedef __attribute__((ext_vector_type(8))) short bf16x8;
typedef __attribute__((ext_vector_type(4))) float f32x4;

#define MFMA_B16(a, b, c) __builtin_amdgcn_mfma_f32_16x16x32_bf16((a), (b), (c), 0, 0, 0)

__device__ __forceinline__ float ssp_f(float v) {
    return fmaxf(v, 0.f) + log1pf(expf(-fabsf(v))) - 0.69314718055994530942f;
}

__device__ __forceinline__ unsigned short f2bf(float x) {
    union { float f; unsigned int u; } v; v.f = x;
    unsigned int r = v.u + 0x7FFFu + ((v.u >> 16) & 1u);
    return (unsigned short)(r >> 16);
}
__device__ __forceinline__ float bf2f(unsigned short h) {
    union { unsigned int u; float f; } v; v.u = ((unsigned int)h) << 16;
    return v.f;
}

union BF8 { bf16x8 v; short s[8]; };

#define LDG4(p) (*reinterpret_cast<const float4*>(p))
#define ST4(p, v) (*reinterpret_cast<float4*>(p) = (v))

#define FMA4(dst, s, vv)                      \
    dst[0] = fmaf((s), (vv).x, dst[0]);       \
    dst[1] = fmaf((s), (vv).y, dst[1]);       \
    dst[2] = fmaf((s), (vv).z, dst[2]);       \
    dst[3] = fmaf((s), (vv).w, dst[3]);

// ---------------------------------------------------------------------------
// k_setup: x = embedding[z]; d (raw distance), fcut per (b,n,k)
// ---------------------------------------------------------------------------
__global__ __launch_bounds__(256) void k_setup(
    const float* __restrict__ pos, const int* __restrict__ zz,
    const int* __restrict__ nbr, const float* __restrict__ nmask,
    const float* __restrict__ emb,
    float* __restrict__ x, float* __restrict__ sd_g, float* __restrict__ fcut)
{
    const int bn = blockIdx.x;
    const int b  = bn >> 7;
    const int t  = threadIdx.x;

    x[bn * Ff + t] = emb[zz[bn] * Ff + t];

    if (t < Kk) {
        int j = nbr[bn * Kk + t];
        float px = pos[bn * 3 + 0], py = pos[bn * 3 + 1], pz = pos[bn * 3 + 2];
        int rj = (b * Nn + j) * 3;
        float dx = pos[rj + 0] - px;
        float dy = pos[rj + 1] - py;
        float dz = pos[rj + 2] - pz;
        float d = sqrtf(fmaf(dx, dx, fmaf(dy, dy, dz * dz)) + 1e-8f);
        sd_g[bn * Kk + t] = d;
        float fc = 0.5f * (cosf(3.14159265358979323846f * d / 5.0f) + 1.0f);
        fc = (d < 5.0f) ? fc : 0.0f;
        fcut[bn * Kk + t] = fc * nmask[bn * Kk + t];
    }
}

// ---------------------------------------------------------------------------
// k_pack256: [t][256][256] f32 -> split bf16, MFMA-B-fragment-major:
// dst[((t*128 + nt16*8 + kk)*64 + lane)*8 + i] holds
// src[k = kk*32+(lane>>4)*8+i][n = nt16*16+(lane&15)].
// Runtime fragment load = base + lane*16B -> fully coalesced.
// ---------------------------------------------------------------------------
__global__ __launch_bounds__(64) void k_pack256(
    const float* __restrict__ src,
    unsigned short* __restrict__ dh, unsigned short* __restrict__ dl)
{
    const int blk  = blockIdx.x;       // t*128 + nt16*8 + kk
    const int t    = blk >> 7;
    const int rem  = blk & 127;
    const int nt16 = rem >> 3;
    const int kk   = rem & 7;
    const int a    = threadIdx.x;
    const int n    = nt16 * 16 + (a & 15);
    const int kb   = kk * 32 + (a >> 4) * 8;
    const size_t dst0 = (((size_t)t * 128 + rem) * 64 + a) * 8;
    #pragma unroll
    for (int i = 0; i < 8; ++i) {
        float v = src[(size_t)t * Ff * Ff + (size_t)(kb + i) * Ff + n];
        unsigned short hi = f2bf(v);
        dh[dst0 + i] = hi;
        dl[dst0 + i] = f2bf(v - bf2f(hi));
    }
}

// ---------------------------------------------------------------------------
// k_pack64: w1 [t][50][256] -> split bf16 fragment-major, K padded to 64
// ---------------------------------------------------------------------------
__global__ __launch_bounds__(64) void k_pack64(
    const float* __restrict__ src,
    unsigned short* __restrict__ dh, unsigned short* __restrict__ dl)
{
    const int blk  = blockIdx.x;       // t*32 + nt16*2 + kk
    const int t    = blk >> 5;
    const int rem  = blk & 31;
    const int nt16 = rem >> 1;
    const int kk   = rem & 1;
    const int a    = threadIdx.x;
    const int n    = nt16 * 16 + (a & 15);
    const int kb   = kk * 32 + (a >> 4) * 8;
    const size_t dst0 = (((size_t)t * 32 + rem) * 64 + a) * 8;
    #pragma unroll
    for (int i = 0; i < 8; ++i) {
        const int k = kb + i;
        float v = (k < Gg) ? src[(size_t)t * Gg * Ff + (size_t)k * Ff + n] : 0.f;
        unsigned short hi = f2bf(v);
        dh[dst0 + i] = hi;
        dl[dst0 + i] = f2bf(v - bf2f(hi));
    }
}

// ---------------------------------------------------------------------------
// k_y16m: y = x @ in2f_w[t], 16 atoms/block, 512 thr = 8 waves,
// wave w owns f-slice [32w,32w+32). B from packed fragments (coalesced).
// ---------------------------------------------------------------------------
__global__ __launch_bounds__(512) void k_y16m(
    const float* __restrict__ x,
    const unsigned short* __restrict__ bhp, const unsigned short* __restrict__ blp,
    float* __restrict__ y)
{
    const int bn0  = blockIdx.x * 16;
    const int tid  = threadIdx.x;
    const int w    = tid >> 6;
    const int lane = tid & 63;
    const int lq   = lane >> 4;
    const int arow = lane & 15;

    f32x4 acc0 = (f32x4){0.f, 0.f, 0.f, 0.f};
    f32x4 acc1 = (f32x4){0.f, 0.f, 0.f, 0.f};
    const float* xrow = x + (size_t)(bn0 + arow) * Ff;

    #pragma unroll 1
    for (int kk = 0; kk < 8; ++kk) {
        const int ko = kk * 32 + lq * 8;
        const float4 a0 = LDG4(&xrow[ko]);
        const float4 a1 = LDG4(&xrow[ko + 4]);
        float av[8] = {a0.x, a0.y, a0.z, a0.w, a1.x, a1.y, a1.z, a1.w};
        BF8 ah, al;
        #pragma unroll
        for (int i = 0; i < 8; ++i) {
            unsigned short h = f2bf(av[i]);
            ah.s[i] = (short)h;
            al.s[i] = (short)f2bf(av[i] - bf2f(h));
        }
        #pragma unroll
        for (int nt = 0; nt < 2; ++nt) {
            const size_t off = ((size_t)((2 * w + nt) * 8 + kk) * 64 + lane) * 8;
            bf16x8 bh = *reinterpret_cast<const bf16x8*>(bhp + off);
            bf16x8 bl = *reinterpret_cast<const bf16x8*>(blp + off);
            f32x4& ac = nt ? acc1 : acc0;
            ac = MFMA_B16(ah.v, bh, ac);
            ac = MFMA_B16(ah.v, bl, ac);
            ac = MFMA_B16(al.v, bh, ac);
        }
    }
    #pragma unroll
    for (int j = 0; j < 4; ++j) {
        y[(size_t)(bn0 + lq * 4 + j) * Ff + w * 32 + arow]      = acc0[j];
        y[(size_t)(bn0 + lq * 4 + j) * Ff + w * 32 + 16 + arow] = acc1[j];
    }
}

// ---------------------------------------------------------------------------
// k_aggm3: one atom per block, 512 thr = 8 waves.
//  layer1 MFMA (fexp in-register A, packed w1 B) -> ssp -> split bf16 ->
//  H stored to LDS in A-FRAGMENT-MAJOR order (layer2 ds_read is lane-linear,
//  conflict-free). layer2 MFMA with packed w2 B (coalesced, read once).
//  Consume writes agg to global ws; f2out is a separate kernel.
//  LDS ~49.5 KB, ONE barrier.
// ---------------------------------------------------------------------------
__global__ __launch_bounds__(512) void k_aggm3(
    const float* __restrict__ sd, const float* __restrict__ fcut,
    const int* __restrict__ nbr, const float* __restrict__ y,
    const unsigned short* __restrict__ w1hp, const unsigned short* __restrict__ w1lp,
    const float* __restrict__ b1,
    const unsigned short* __restrict__ whp, const unsigned short* __restrict__ wlp,
    const float* __restrict__ b2,
    float* __restrict__ agg)
{
    const int bn    = blockIdx.x;
    const int bbase = (bn >> 7) << 7;       // b * 128
    const int tid   = threadIdx.x;
    const int w     = tid >> 6;
    const int lane  = tid & 63;
    const int lq    = lane >> 4;
    const int arow  = lane & 15;

    __shared__ __align__(16) unsigned short HhP[3 * 8 * 64 * 8];  // 24576 B
    __shared__ __align__(16) unsigned short HlP[3 * 8 * 64 * 8];  // 24576 B
    __shared__ float scut[Kk];
    __shared__ int   snbr[Kk];

    if (tid < Kk) {
        scut[tid] = fcut[bn * Kk + tid];
        snbr[tid] = nbr[bn * Kk + tid];
    }

    const float step = 5.0f / 49.0f;
    const float coeff = -0.5f / (step * step);

    // ================= layer 1 (MFMA), 3 m-tiles, no barriers ================
    #pragma unroll 1
    for (int mt = 0; mt < 3; ++mt) {
        const float d = sd[bn * Kk + mt * 16 + arow];

        BF8 fah[2], fal[2];
        #pragma unroll
        for (int kk = 0; kk < 2; ++kk) {
            #pragma unroll
            for (int i = 0; i < 8; ++i) {
                const int g = kk * 32 + lq * 8 + i;
                float dd = d - step * (float)g;
                float val = (g < Gg) ? expf(coeff * dd * dd) : 0.f;
                unsigned short h = f2bf(val);
                fah[kk].s[i] = (short)h;
                fal[kk].s[i] = (short)f2bf(val - bf2f(h));
            }
        }

        f32x4 acc1[2];
        acc1[0] = (f32x4){0.f, 0.f, 0.f, 0.f};
        acc1[1] = (f32x4){0.f, 0.f, 0.f, 0.f};

        #pragma unroll
        for (int kk = 0; kk < 2; ++kk) {
            #pragma unroll
            for (int nt = 0; nt < 2; ++nt) {
                const size_t off = ((size_t)((2 * w + nt) * 2 + kk) * 64 + lane) * 8;
                bf16x8 bh = *reinterpret_cast<const bf16x8*>(w1hp + off);
                bf16x8 bl = *reinterpret_cast<const bf16x8*>(w1lp + off);
                acc1[nt] = MFMA_B16(fah[kk].v, bh, acc1[nt]);
                acc1[nt] = MFMA_B16(fah[kk].v, bl, acc1[nt]);
                acc1[nt] = MFMA_B16(fal[kk].v, bh, acc1[nt]);
            }
        }

        // D(row = lq*4+j, col = w*32+nt*16+arow) -> ssp -> split ->
        // A-fragment-major LDS: tile (mt, kk2=w), lane a, elem i
        #pragma unroll
        for (int nt = 0; nt < 2; ++nt) {
            const int col = w * 32 + nt * 16 + arow;
            const float b1v = b1[col];
            const int a_ = (nt * 2 + (arow >> 3)) << 4;   // high bits of frag lane
            const int i_ = arow & 7;
            #pragma unroll
            for (int j = 0; j < 4; ++j) {
                float v = ssp_f(acc1[nt][j] + b1v);
                unsigned short hh = f2bf(v);
                unsigned short ll = f2bf(v - bf2f(hh));
                const int fl = (lq * 4 + j) | a_;          // fragment lane
                const int idx = ((mt * 8 + w) * 64 + fl) * 8 + i_;
                HhP[idx] = hh;
                HlP[idx] = ll;
            }
        }
    }
    __syncthreads();

    // ================= layer 2 (MFMA): kk-outer, B once per block ===========
    f32x4 acc[3][2];
    #pragma unroll
    for (int mt = 0; mt < 3; ++mt) {
        acc[mt][0] = (f32x4){0.f, 0.f, 0.f, 0.f};
        acc[mt][1] = (f32x4){0.f, 0.f, 0.f, 0.f};
    }

    #pragma unroll 1
    for (int kk = 0; kk < 8; ++kk) {
        bf16x8 bh[2], bl[2];
        #pragma unroll
        for (int nt = 0; nt < 2; ++nt) {
            const size_t off = ((size_t)((2 * w + nt) * 8 + kk) * 64 + lane) * 8;
            bh[nt] = *reinterpret_cast<const bf16x8*>(whp + off);
            bl[nt] = *reinterpret_cast<const bf16x8*>(wlp + off);
        }
        #pragma unroll
        for (int mt = 0; mt < 3; ++mt) {
            const int abase = ((mt * 8 + kk) * 64 + lane) * 8;
            bf16x8 ah = *reinterpret_cast<const bf16x8*>(&HhP[abase]);
            bf16x8 al = *reinterpret_cast<const bf16x8*>(&HlP[abase]);
            #pragma unroll
            for (int nt = 0; nt < 2; ++nt) {
                acc[mt][nt] = MFMA_B16(ah, bh[nt], acc[mt][nt]);
                acc[mt][nt] = MFMA_B16(ah, bl[nt], acc[mt][nt]);
                acc[mt][nt] = MFMA_B16(al, bh[nt], acc[mt][nt]);
            }
        }
    }

    // ================= consume: cutoff + neighbor y gather ===================
    float b2v0 = b2[w * 32 + arow];
    float b2v1 = b2[w * 32 + 16 + arow];

    float aggp0 = 0.f, aggp1 = 0.f;
    #pragma unroll
    for (int mt = 0; mt < 3; ++mt) {
        #pragma unroll
        for (int j = 0; j < 4; ++j) {
            const int r = mt * 16 + lq * 4 + j;
            const float ct = scut[r];
            const int   nb = snbr[r];
            const float* yr = y + (size_t)(bbase + nb) * Ff + w * 32 + arow;
            aggp0 = fmaf((acc[mt][0][j] + b2v0) * ct, yr[0],  aggp0);
            aggp1 = fmaf((acc[mt][1][j] + b2v1) * ct, yr[16], aggp1);
        }
    }
    aggp0 += __shfl_xor(aggp0, 16);
    aggp0 += __shfl_xor(aggp0, 32);
    aggp1 += __shfl_xor(aggp1, 16);
    aggp1 += __shfl_xor(aggp1, 32);
    if (lq == 0) {
        agg[(size_t)bn * Ff + w * 32 + arow]      = aggp0;
        agg[(size_t)bn * Ff + w * 32 + 16 + arow] = aggp1;
    }
}

// ---------------------------------------------------------------------------
// k_f2out: x += ssp(agg@fw1+fb1)@fw2+fb2, 8 atoms per block (VALU),
// weights amortized 8x, 256 thr.
// ---------------------------------------------------------------------------
__global__ __launch_bounds__(256) void k_f2out(
    const float* __restrict__ agg,
    const float* __restrict__ fw1, const float* __restrict__ fb1,
    const float* __restrict__ fw2, const float* __restrict__ fb2,
    float* __restrict__ x)
{
    const int bn0 = blockIdx.x * 8;
    const int tid = threadIdx.x;
    const int tx  = tid & 63;
    const int ty  = tid >> 6;
    const int f4  = tx * 4;

    __shared__ __align__(16) float sin_[8][Ff];     // 8 KB (agg, then sv)
    __shared__ __align__(16) float part[4][8][Ff];  // 32 KB

    #pragma unroll
    for (int a = 0; a < 8; ++a)
        sin_[a][tid] = agg[(size_t)(bn0 + a) * Ff + tid];
    __syncthreads();

    // ---- matvec 1 ----
    {
        float p[8][4];
        #pragma unroll
        for (int a = 0; a < 8; ++a) { p[a][0] = 0.f; p[a][1] = 0.f; p[a][2] = 0.f; p[a][3] = 0.f; }
        #pragma unroll 1
        for (int c = 0; c < 8; ++c) {
            const int h0 = ty * 64 + c * 8;
            float4 wq[8];
            #pragma unroll
            for (int j = 0; j < 8; ++j)
                wq[j] = LDG4(&fw1[(h0 + j) * Ff + f4]);
            #pragma unroll
            for (int a = 0; a < 8; ++a) {
                const float4 a0 = LDG4(&sin_[a][h0]);
                const float4 a1 = LDG4(&sin_[a][h0 + 4]);
                FMA4(p[a], a0.x, wq[0]); FMA4(p[a], a0.y, wq[1]);
                FMA4(p[a], a0.z, wq[2]); FMA4(p[a], a0.w, wq[3]);
                FMA4(p[a], a1.x, wq[4]); FMA4(p[a], a1.y, wq[5]);
                FMA4(p[a], a1.z, wq[6]); FMA4(p[a], a1.w, wq[7]);
            }
        }
        #pragma unroll
        for (int a = 0; a < 8; ++a)
            ST4(&part[ty][a][f4], make_float4(p[a][0], p[a][1], p[a][2], p[a][3]));
    }
    __syncthreads();
    {
        const float fb = fb1[tid];
        #pragma unroll
        for (int a = 0; a < 8; ++a) {
            float u = part[0][a][tid] + part[1][a][tid]
                    + part[2][a][tid] + part[3][a][tid] + fb;
            sin_[a][tid] = ssp_f(u);
        }
    }
    __syncthreads();

    // ---- matvec 2 + residual ----
    {
        float p[8][4];
        #pragma unroll
        for (int a = 0; a < 8; ++a) { p[a][0] = 0.f; p[a][1] = 0.f; p[a][2] = 0.f; p[a][3] = 0.f; }
        #pragma unroll 1
        for (int c = 0; c < 8; ++c) {
            const int h0 = ty * 64 + c * 8;
            float4 wq[8];
            #pragma unroll
            for (int j = 0; j < 8; ++j)
                wq[j] = LDG4(&fw2[(h0 + j) * Ff + f4]);
            #pragma unroll
            for (int a = 0; a < 8; ++a) {
                const float4 a0 = LDG4(&sin_[a][h0]);
                const float4 a1 = LDG4(&sin_[a][h0 + 4]);
                FMA4(p[a], a0.x, wq[0]); FMA4(p[a], a0.y, wq[1]);
                FMA4(p[a], a0.z, wq[2]); FMA4(p[a], a0.w, wq[3]);
                FMA4(p[a], a1.x, wq[4]); FMA4(p[a], a1.y, wq[5]);
                FMA4(p[a], a1.z, wq[6]); FMA4(p[a], a1.w, wq[7]);
            }
        }
        #pragma unroll
        for (int a = 0; a < 8; ++a)
            ST4(&part[ty][a][f4], make_float4(p[a][0], p[a][1], p[a][2], p[a][3]));
    }
    __syncthreads();
    {
        const float fb = fb2[tid];
        #pragma unroll
        for (int a = 0; a < 8; ++a) {
            float o = part[0][a][tid] + part[1][a][tid]
                    + part[2][a][tid] + part[3][a][tid] + fb;
            x[(size_t)(bn0 + a) * Ff + tid] += o;
        }
    }
}

// ---------------------------------------------------------------------------
// k_head: disp/frac/rep, predictor MLP, masked mean, new_cell, new_pos
// ---------------------------------------------------------------------------
__global__ __launch_bounds__(128) void k_head(
    const float* __restrict__ x, const float* __restrict__ pos,
    const float* __restrict__ cell, const float* __restrict__ amask,
    const float* __restrict__ fdw, const float* __restrict__ fdb,
    const float* __restrict__ pw1, const float* __restrict__ pb1,
    const float* __restrict__ pw2, const float* __restrict__ pb2,
    float* __restrict__ out_pos, float* __restrict__ out_cell)
{
    const int b = blockIdx.x;
    const int n = threadIdx.x;

    __shared__ float sinv[9];
    __shared__ float scell[9];
    __shared__ float snc[9];
    __shared__ float sred[Nn][10];

    if (n == 0) {
        float c[9];
        #pragma unroll
        for (int i = 0; i < 9; ++i) { c[i] = cell[b * 9 + i]; scell[i] = c[i]; }
        float det = c[0] * (c[4] * c[8] - c[5] * c[7])
                  - c[1] * (c[3] * c[8] - c[5] * c[6])
                  + c[2] * (c[3] * c[7] - c[4] * c[6]);
        float id = 1.0f / det;
        sinv[0] = (c[4] * c[8] - c[5] * c[7]) * id;
        sinv[1] = (c[2] * c[7] - c[1] * c[8]) * id;
        sinv[2] = (c[1] * c[5] - c[2] * c[4]) * id;
        sinv[3] = (c[5] * c[6] - c[3] * c[8]) * id;
        sinv[4] = (c[0] * c[8] - c[2] * c[6]) * id;
        sinv[5] = (c[2] * c[3] - c[0] * c[5]) * id;
        sinv[6] = (c[3] * c[7] - c[4] * c[6]) * id;
        sinv[7] = (c[1] * c[6] - c[0] * c[7]) * id;
        sinv[8] = (c[0] * c[4] - c[1] * c[3]) * id;
    }
    __syncthreads();

    float xv0 = 0.f, xv1 = 0.f, xv2 = 0.f;
    const int row = (b * Nn + n) * Ff;
    for (int ff = 0; ff < Ff; ++ff) {
        float xr = x[row + ff];
        xv0 = fmaf(xr, fdw[ff * 3 + 0], xv0);
        xv1 = fmaf(xr, fdw[ff * 3 + 1], xv1);
        xv2 = fmaf(xr, fdw[ff * 3 + 2], xv2);
    }
    float fr[3];
    float dsp[3] = {xv0, xv1, xv2};
    const float p0 = pos[(b * Nn + n) * 3 + 0];
    const float p1 = pos[(b * Nn + n) * 3 + 1];
    const float p2 = pos[(b * Nn + n) * 3 + 2];
    #pragma unroll
    for (int j = 0; j < 3; ++j) {
        float z = 10.0f * (dsp[j] + fdb[j]);
        float s = 1.0f / (1.0f + expf(-z));
        float fx = p0 * sinv[0 * 3 + j] + p1 * sinv[1 * 3 + j] + p2 * sinv[2 * 3 + j] + s;
        fr[j] = fx - floorf(fx);
    }

    float rep[3];
    #pragma unroll
    for (int j = 0; j < 3; ++j)
        rep[j] = fr[0] * scell[0 * 3 + j] + fr[1] * scell[1 * 3 + j] + fr[2] * scell[2 * 3 + j];

    float a6[6];
    #pragma unroll
    for (int i = 0; i < 6; ++i) {
        float uv = rep[0] * pw1[0 * 6 + i] + rep[1] * pw1[1 * 6 + i]
                 + rep[2] * pw1[2 * 6 + i] + pb1[i];
        a6[i] = ssp_f(uv);
    }
    float h9[9];
    #pragma unroll
    for (int o = 0; o < 9; ++o) {
        float uv = pb2[o];
        #pragma unroll
        for (int i = 0; i < 6; ++i) uv = fmaf(a6[i], pw2[i * 9 + o], uv);
        h9[o] = uv;
    }

    const float m = amask[b * Nn + n];
    #pragma unroll
    for (int o = 0; o < 9; ++o) sred[n][o] = h9[o] * m;
    sred[n][9] = m;
    __syncthreads();

    for (int s = 64; s >= 1; s >>= 1) {
        if (n < s) {
            #pragma unroll
            for (int o = 0; o < 10; ++o) sred[n][o] += sred[n + s][o];
        }
        __syncthreads();
    }

    if (n < 9) {
        float na = sred[0][9];
        float yo = sred[0][n] / na;
        float scale = 3.0f * powf(na, 1.0f / 3.0f);
        int r = n / 3, c = n - r * 3;
        float v = scale * (((r == c) ? 1.0f : 0.0f) + yo);
        snc[n] = v;
        out_cell[b * 9 + n] = v;
    }
    __syncthreads();

    #pragma unroll
    for (int j = 0; j < 3; ++j) {
        float v = fr[0] * snc[0 * 3 + j] + fr[1] * snc[1 * 3 + j] + fr[2] * snc[2 * 3 + j];
        out_pos[(b * Nn + n) * 3 + j] = v;
    }
}

// ---------------------------------------------------------------------------
extern "C" void kernel_launch(void* const* d_in, const int* in_sizes, int n_in,
                              void* d_out, int out_size, void* d_ws, size_t ws_size,
                              hipStream_t stream)
{
    const float* positions     = (const float*)d_in[0];
    const float* cell          = (const float*)d_in[1];
    const int*   atomic_nums   = (const int*)  d_in[2];
    const int*   neighbors     = (const int*)  d_in[3];
    const float* neighbor_mask = (const float*)d_in[4];
    const float* atom_mask     = (const float*)d_in[5];
    const float* embedding     = (const float*)d_in[6];
    const float* filt_w1       = (const float*)d_in[7];
    const float* filt_b1       = (const float*)d_in[8];
    const float* filt_w2       = (const float*)d_in[9];
    const float* filt_b2       = (const float*)d_in[10];
    const float* in2f_w        = (const float*)d_in[11];
    const float* f2out_w1      = (const float*)d_in[12];
    const float* f2out_b1      = (const float*)d_in[13];
    const float* f2out_w2      = (const float*)d_in[14];
    const float* f2out_b2      = (const float*)d_in[15];
    const float* fd_w          = (const float*)d_in[16];
    const float* fd_b          = (const float*)d_in[17];
    const float* pred_w1       = (const float*)d_in[18];
    const float* pred_b1       = (const float*)d_in[19];
    const float* pred_w2       = (const float*)d_in[20];
    const float* pred_b2       = (const float*)d_in[21];

    float* ws   = (float*)d_ws;
    float* x    = ws;                          // 1048576 f32
    float* y    = x + Bb * Nn * Ff;            // 1048576 f32
    float* agg  = y + Bb * Nn * Ff;            // 1048576 f32
    float* sd   = agg + Bb * Nn * Ff;          // 196608 f32
    float* fcut = sd + Bb * Nn * Kk;           // 196608 f32
    unsigned short* whp  = (unsigned short*)(fcut + Bb * Nn * Kk);
    unsigned short* wlp  = whp + (size_t)Tt * Ff * Ff;
    unsigned short* ihp  = wlp + (size_t)Tt * Ff * Ff;
    unsigned short* ilp  = ihp + (size_t)Tt * Ff * Ff;
    unsigned short* w1hp = ilp + (size_t)Tt * Ff * Ff;
    unsigned short* w1lp = w1hp + (size_t)Tt * Ff * 64;

    float* out_pos  = (float*)d_out;
    float* out_cell = out_pos + Bb * Nn * 3;

    const int BN = Bb * Nn;

    k_setup<<<BN, 256, 0, stream>>>(positions, atomic_nums, neighbors,
                                    neighbor_mask, embedding, x, sd, fcut);
    k_pack256<<<Tt * 128, 64, 0, stream>>>(filt_w2, whp, wlp);
    k_pack256<<<Tt * 128, 64, 0, stream>>>(in2f_w, ihp, ilp);
    k_pack64<<<Tt * 32, 64, 0, stream>>>(filt_w1, w1hp, w1lp);

    for (int t = 0; t < Tt; ++t) {
        k_y16m<<<BN / 16, 512, 0, stream>>>(x,
                                            ihp + (size_t)t * Ff * Ff,
                                            ilp + (size_t)t * Ff * Ff,
                                            y);
        k_aggm3<<<BN, 512, 0, stream>>>(sd, fcut, neighbors, y,
                                        w1hp + (size_t)t * Ff * 64,
                                        w1lp + (size_t)t * Ff * 64,
                                        filt_b1 + (size_t)t * Ff,
                                        whp + (size_t)t * Ff * Ff,
                                        wlp + (size_t)t * Ff * Ff,
                                        filt_b2 + (size_t)t * Ff,
                                        agg);
        k_f2out<<<BN / 8, 256, 0, stream>>>(agg,
                                            f2out_w1 + (size_t)t * Ff * Ff,
                                            f2out_b1 + (size_t)t * Ff,
                                            f2out_w2 + (size_t)t * Ff * Ff,
                                            f2out_b2 + (size_t)t * Ff,
                                            x);
    }

    k_head<<<Bb, 128, 0, stream>>>(x, positions, cell, atom_mask,
                                   fd_w, fd_b, pred_w1, pred_b1, pred_w2, pred_b2,
                                   out_pos, out_cell);
}

// Round 17
// 800.765 us; speedup vs baseline: 1.0015x; 1.0015x over previous
//
#include <hip/hip_runtime.h>
#include <math.h>

#define Bb 32
#define Nn 128
#define Kk 48
#define Ff 256
#define Gg 50
#define Tt 3

typedef __attribute__((ext_vector_type(8))) short bf16x8;
typedef __attribute__((ext_vector_type(4))) float f32x4;

#define MFMA_B16(a, b, c) __builtin_amdgcn_mfma_f32_16x16x32_bf16((a), (b), (c), 0, 0, 0)

__device__ __forceinline__ float ssp_f(float v) {
    return fmaxf(v, 0.f) + log1pf(expf(-fabsf(v))) - 0.69314718055994530942f;
}

__device__ __forceinline__ unsigned short f2bf(float x) {
    union { float f; unsigned int u; } v; v.f = x;
    unsigned int r = v.u + 0x7FFFu + ((v.u >> 16) & 1u);
    return (unsigned short)(r >> 16);
}
__device__ __forceinline__ float bf2f(unsigned short h) {
    union { unsigned int u; float f; } v; v.u = ((unsigned int)h) << 16;
    return v.f;
}

union BF8 { bf16x8 v; short s[8]; };

#define LDG4(p) (*reinterpret_cast<const float4*>(p))
#define ST4(p, v) (*reinterpret_cast<float4*>(p) = (v))

#define FMA4(dst, s, vv)                      \
    dst[0] = fmaf((s), (vv).x, dst[0]);       \
    dst[1] = fmaf((s), (vv).y, dst[1]);       \
    dst[2] = fmaf((s), (vv).z, dst[2]);       \
    dst[3] = fmaf((s), (vv).w, dst[3]);

// ---------------------------------------------------------------------------
// k_setup: x = embedding[z]; d (raw distance), fcut per (b,n,k)
// ---------------------------------------------------------------------------
__global__ __launch_bounds__(256) void k_setup(
    const float* __restrict__ pos, const int* __restrict__ zz,
    const int* __restrict__ nbr, const float* __restrict__ nmask,
    const float* __restrict__ emb,
    float* __restrict__ x, float* __restrict__ sd_g, float* __restrict__ fcut)
{
    const int bn = blockIdx.x;
    const int b  = bn >> 7;
    const int t  = threadIdx.x;

    x[bn * Ff + t] = emb[zz[bn] * Ff + t];

    if (t < Kk) {
        int j = nbr[bn * Kk + t];
        float px = pos[bn * 3 + 0], py = pos[bn * 3 + 1], pz = pos[bn * 3 + 2];
        int rj = (b * Nn + j) * 3;
        float dx = pos[rj + 0] - px;
        float dy = pos[rj + 1] - py;
        float dz = pos[rj + 2] - pz;
        float d = sqrtf(fmaf(dx, dx, fmaf(dy, dy, dz * dz)) + 1e-8f);
        sd_g[bn * Kk + t] = d;
        float fc = 0.5f * (cosf(3.14159265358979323846f * d / 5.0f) + 1.0f);
        fc = (d < 5.0f) ? fc : 0.0f;
        fcut[bn * Kk + t] = fc * nmask[bn * Kk + t];
    }
}

// ---------------------------------------------------------------------------
// k_pack256: [t][256][256] f32 -> split bf16, MFMA-B-fragment-major:
// dst[((t*128 + nt16*8 + kk)*64 + lane)*8 + i] holds
// src[k = kk*32+(lane>>4)*8+i][n = nt16*16+(lane&15)].
// Runtime fragment load = base + lane*16B -> fully coalesced.
// ---------------------------------------------------------------------------
__global__ __launch_bounds__(64) void k_pack256(
    const float* __restrict__ src,
    unsigned short* __restrict__ dh, unsigned short* __restrict__ dl)
{
    const int blk  = blockIdx.x;       // t*128 + nt16*8 + kk
    const int t    = blk >> 7;
    const int rem  = blk & 127;
    const int nt16 = rem >> 3;
    const int kk   = rem & 7;
    const int a    = threadIdx.x;
    const int n    = nt16 * 16 + (a & 15);
    const int kb   = kk * 32 + (a >> 4) * 8;
    const size_t dst0 = (((size_t)t * 128 + rem) * 64 + a) * 8;
    #pragma unroll
    for (int i = 0; i < 8; ++i) {
        float v = src[(size_t)t * Ff * Ff + (size_t)(kb + i) * Ff + n];
        unsigned short hi = f2bf(v);
        dh[dst0 + i] = hi;
        dl[dst0 + i] = f2bf(v - bf2f(hi));
    }
}

// ---------------------------------------------------------------------------
// k_pack64: w1 [t][50][256] -> split bf16 fragment-major, K padded to 64
// ---------------------------------------------------------------------------
__global__ __launch_bounds__(64) void k_pack64(
    const float* __restrict__ src,
    unsigned short* __restrict__ dh, unsigned short* __restrict__ dl)
{
    const int blk  = blockIdx.x;       // t*32 + nt16*2 + kk
    const int t    = blk >> 5;
    const int rem  = blk & 31;
    const int nt16 = rem >> 1;
    const int kk   = rem & 1;
    const int a    = threadIdx.x;
    const int n    = nt16 * 16 + (a & 15);
    const int kb   = kk * 32 + (a >> 4) * 8;
    const size_t dst0 = (((size_t)t * 32 + rem) * 64 + a) * 8;
    #pragma unroll
    for (int i = 0; i < 8; ++i) {
        const int k = kb + i;
        float v = (k < Gg) ? src[(size_t)t * Gg * Ff + (size_t)k * Ff + n] : 0.f;
        unsigned short hi = f2bf(v);
        dh[dst0 + i] = hi;
        dl[dst0 + i] = f2bf(v - bf2f(hi));
    }
}

// ---------------------------------------------------------------------------
// k_y16m: y = x @ in2f_w[t], 16 atoms/block, 512 thr = 8 waves,
// wave w owns f-slice [32w,32w+32). B from packed fragments (coalesced).
// ---------------------------------------------------------------------------
__global__ __launch_bounds__(512) void k_y16m(
    const float* __restrict__ x,
    const unsigned short* __restrict__ bhp, const unsigned short* __restrict__ blp,
    float* __restrict__ y)
{
    const int bn0  = blockIdx.x * 16;
    const int tid  = threadIdx.x;
    const int w    = tid >> 6;
    const int lane = tid & 63;
    const int lq   = lane >> 4;
    const int arow = lane & 15;

    f32x4 acc0 = (f32x4){0.f, 0.f, 0.f, 0.f};
    f32x4 acc1 = (f32x4){0.f, 0.f, 0.f, 0.f};
    const float* xrow = x + (size_t)(bn0 + arow) * Ff;

    #pragma unroll 1
    for (int kk = 0; kk < 8; ++kk) {
        const int ko = kk * 32 + lq * 8;
        const float4 a0 = LDG4(&xrow[ko]);
        const float4 a1 = LDG4(&xrow[ko + 4]);
        float av[8] = {a0.x, a0.y, a0.z, a0.w, a1.x, a1.y, a1.z, a1.w};
        BF8 ah, al;
        #pragma unroll
        for (int i = 0; i < 8; ++i) {
            unsigned short h = f2bf(av[i]);
            ah.s[i] = (short)h;
            al.s[i] = (short)f2bf(av[i] - bf2f(h));
        }
        #pragma unroll
        for (int nt = 0; nt < 2; ++nt) {
            const size_t off = ((size_t)((2 * w + nt) * 8 + kk) * 64 + lane) * 8;
            bf16x8 bh = *reinterpret_cast<const bf16x8*>(bhp + off);
            bf16x8 bl = *reinterpret_cast<const bf16x8*>(blp + off);
            f32x4& ac = nt ? acc1 : acc0;
            ac = MFMA_B16(ah.v, bh, ac);
            ac = MFMA_B16(ah.v, bl, ac);
            ac = MFMA_B16(al.v, bh, ac);
        }
    }
    #pragma unroll
    for (int j = 0; j < 4; ++j) {
        y[(size_t)(bn0 + lq * 4 + j) * Ff + w * 32 + arow]      = acc0[j];
        y[(size_t)(bn0 + lq * 4 + j) * Ff + w * 32 + 16 + arow] = acc1[j];
    }
}

// ---------------------------------------------------------------------------
// k_aggm3: one atom per block, 512 thr = 8 waves.
//  layer1 MFMA (fexp in-register A, packed w1 B) -> ssp -> split bf16 ->
//  H stored to LDS in A-FRAGMENT-MAJOR order (layer2 ds_read is lane-linear,
//  conflict-free). layer2 MFMA with packed w2 B (coalesced, read once).
//  Consume writes agg to global ws; f2out is a separate kernel.
//  LDS ~49.5 KB, ONE barrier.
// ---------------------------------------------------------------------------
__global__ __launch_bounds__(512) void k_aggm3(
    const float* __restrict__ sd, const float* __restrict__ fcut,
    const int* __restrict__ nbr, const float* __restrict__ y,
    const unsigned short* __restrict__ w1hp, const unsigned short* __restrict__ w1lp,
    const float* __restrict__ b1,
    const unsigned short* __restrict__ whp, const unsigned short* __restrict__ wlp,
    const float* __restrict__ b2,
    float* __restrict__ agg)
{
    const int bn    = blockIdx.x;
    const int bbase = (bn >> 7) << 7;       // b * 128
    const int tid   = threadIdx.x;
    const int w     = tid >> 6;
    const int lane  = tid & 63;
    const int lq    = lane >> 4;
    const int arow  = lane & 15;

    __shared__ __align__(16) unsigned short HhP[3 * 8 * 64 * 8];  // 24576 B
    __shared__ __align__(16) unsigned short HlP[3 * 8 * 64 * 8];  // 24576 B
    __shared__ float scut[Kk];
    __shared__ int   snbr[Kk];

    if (tid < Kk) {
        scut[tid] = fcut[bn * Kk + tid];
        snbr[tid] = nbr[bn * Kk + tid];
    }

    const float step = 5.0f / 49.0f;
    const float coeff = -0.5f / (step * step);

    // ================= layer 1 (MFMA), 3 m-tiles, no barriers ================
    #pragma unroll 1
    for (int mt = 0; mt < 3; ++mt) {
        const float d = sd[bn * Kk + mt * 16 + arow];

        BF8 fah[2], fal[2];
        #pragma unroll
        for (int kk = 0; kk < 2; ++kk) {
            #pragma unroll
            for (int i = 0; i < 8; ++i) {
                const int g = kk * 32 + lq * 8 + i;
                float dd = d - step * (float)g;
                float val = (g < Gg) ? expf(coeff * dd * dd) : 0.f;
                unsigned short h = f2bf(val);
                fah[kk].s[i] = (short)h;
                fal[kk].s[i] = (short)f2bf(val - bf2f(h));
            }
        }

        f32x4 acc1[2];
        acc1[0] = (f32x4){0.f, 0.f, 0.f, 0.f};
        acc1[1] = (f32x4){0.f, 0.f, 0.f, 0.f};

        #pragma unroll
        for (int kk = 0; kk < 2; ++kk) {
            #pragma unroll
            for (int nt = 0; nt < 2; ++nt) {
                const size_t off = ((size_t)((2 * w + nt) * 2 + kk) * 64 + lane) * 8;
                bf16x8 bh = *reinterpret_cast<const bf16x8*>(w1hp + off);
                bf16x8 bl = *reinterpret_cast<const bf16x8*>(w1lp + off);
                acc1[nt] = MFMA_B16(fah[kk].v, bh, acc1[nt]);
                acc1[nt] = MFMA_B16(fah[kk].v, bl, acc1[nt]);
                acc1[nt] = MFMA_B16(fal[kk].v, bh, acc1[nt]);
            }
        }

        // D(row = lq*4+j, col = w*32+nt*16+arow) -> ssp -> split ->
        // A-fragment-major LDS: tile (mt, kk2=w), lane a, elem i
        #pragma unroll
        for (int nt = 0; nt < 2; ++nt) {
            const int col = w * 32 + nt * 16 + arow;
            const float b1v = b1[col];
            const int a_ = (nt * 2 + (arow >> 3)) << 4;   // high bits of frag lane
            const int i_ = arow & 7;
            #pragma unroll
            for (int j = 0; j < 4; ++j) {
                float v = ssp_f(acc1[nt][j] + b1v);
                unsigned short hh = f2bf(v);
                unsigned short ll = f2bf(v - bf2f(hh));
                const int fl = (lq * 4 + j) | a_;          // fragment lane
                const int idx = ((mt * 8 + w) * 64 + fl) * 8 + i_;
                HhP[idx] = hh;
                HlP[idx] = ll;
            }
        }
    }
    __syncthreads();

    // ================= layer 2 (MFMA): kk-outer, B once per block ===========
    f32x4 acc[3][2];
    #pragma unroll
    for (int mt = 0; mt < 3; ++mt) {
        acc[mt][0] = (f32x4){0.f, 0.f, 0.f, 0.f};
        acc[mt][1] = (f32x4){0.f, 0.f, 0.f, 0.f};
    }

    #pragma unroll 1
    for (int kk = 0; kk < 8; ++kk) {
        bf16x8 bh[2], bl[2];
        #pragma unroll
        for (int nt = 0; nt < 2; ++nt) {
            const size_t off = ((size_t)((2 * w + nt) * 8 + kk) * 64 + lane) * 8;
            bh[nt] = *reinterpret_cast<const bf16x8*>(whp + off);
            bl[nt] = *reinterpret_cast<const bf16x8*>(wlp + off);
        }
        #pragma unroll
        for (int mt = 0; mt < 3; ++mt) {
            const int abase = ((mt * 8 + kk) * 64 + lane) * 8;
            bf16x8 ah = *reinterpret_cast<const bf16x8*>(&HhP[abase]);
            bf16x8 al = *reinterpret_cast<const bf16x8*>(&HlP[abase]);
            #pragma unroll
            for (int nt = 0; nt < 2; ++nt) {
                acc[mt][nt] = MFMA_B16(ah, bh[nt], acc[mt][nt]);
                acc[mt][nt] = MFMA_B16(ah, bl[nt], acc[mt][nt]);
                acc[mt][nt] = MFMA_B16(al, bh[nt], acc[mt][nt]);
            }
        }
    }

    // ================= consume: cutoff + neighbor y gather ===================
    float b2v0 = b2[w * 32 + arow];
    float b2v1 = b2[w * 32 + 16 + arow];

    float aggp0 = 0.f, aggp1 = 0.f;
    #pragma unroll
    for (int mt = 0; mt < 3; ++mt) {
        #pragma unroll
        for (int j = 0; j < 4; ++j) {
            const int r = mt * 16 + lq * 4 + j;
            const float ct = scut[r];
            const int   nb = snbr[r];
            const float* yr = y + (size_t)(bbase + nb) * Ff + w * 32 + arow;
            aggp0 = fmaf((acc[mt][0][j] + b2v0) * ct, yr[0],  aggp0);
            aggp1 = fmaf((acc[mt][1][j] + b2v1) * ct, yr[16], aggp1);
        }
    }
    aggp0 += __shfl_xor(aggp0, 16);
    aggp0 += __shfl_xor(aggp0, 32);
    aggp1 += __shfl_xor(aggp1, 16);
    aggp1 += __shfl_xor(aggp1, 32);
    if (lq == 0) {
        agg[(size_t)bn * Ff + w * 32 + arow]      = aggp0;
        agg[(size_t)bn * Ff + w * 32 + 16 + arow] = aggp1;
    }
}

// ---------------------------------------------------------------------------
// k_f2out: x += ssp(agg@fw1+fb1)@fw2+fb2, 8 atoms per block (VALU),
// weights amortized 8x, 256 thr.
// ---------------------------------------------------------------------------
__global__ __launch_bounds__(256) void k_f2out(
    const float* __restrict__ agg,
    const float* __restrict__ fw1, const float* __restrict__ fb1,
    const float* __restrict__ fw2, const float* __restrict__ fb2,
    float* __restrict__ x)
{
    const int bn0 = blockIdx.x * 8;
    const int tid = threadIdx.x;
    const int tx  = tid & 63;
    const int ty  = tid >> 6;
    const int f4  = tx * 4;

    __shared__ __align__(16) float sin_[8][Ff];     // 8 KB (agg, then sv)
    __shared__ __align__(16) float part[4][8][Ff];  // 32 KB

    #pragma unroll
    for (int a = 0; a < 8; ++a)
        sin_[a][tid] = agg[(size_t)(bn0 + a) * Ff + tid];
    __syncthreads();

    // ---- matvec 1 ----
    {
        float p[8][4];
        #pragma unroll
        for (int a = 0; a < 8; ++a) { p[a][0] = 0.f; p[a][1] = 0.f; p[a][2] = 0.f; p[a][3] = 0.f; }
        #pragma unroll 1
        for (int c = 0; c < 8; ++c) {
            const int h0 = ty * 64 + c * 8;
            float4 wq[8];
            #pragma unroll
            for (int j = 0; j < 8; ++j)
                wq[j] = LDG4(&fw1[(h0 + j) * Ff + f4]);
            #pragma unroll
            for (int a = 0; a < 8; ++a) {
                const float4 a0 = LDG4(&sin_[a][h0]);
                const float4 a1 = LDG4(&sin_[a][h0 + 4]);
                FMA4(p[a], a0.x, wq[0]); FMA4(p[a], a0.y, wq[1]);
                FMA4(p[a], a0.z, wq[2]); FMA4(p[a], a0.w, wq[3]);
                FMA4(p[a], a1.x, wq[4]); FMA4(p[a], a1.y, wq[5]);
                FMA4(p[a], a1.z, wq[6]); FMA4(p[a], a1.w, wq[7]);
            }
        }
        #pragma unroll
        for (int a = 0; a < 8; ++a)
            ST4(&part[ty][a][f4], make_float4(p[a][0], p[a][1], p[a][2], p[a][3]));
    }
    __syncthreads();
    {
        const float fb = fb1[tid];
        #pragma unroll
        for (int a = 0; a < 8; ++a) {
            float u = part[0][a][tid] + part[1][a][tid]
                    + part[2][a][tid] + part[3][a][tid] + fb;
            sin_[a][tid] = ssp_f(u);
        }
    }
    __syncthreads();

    // ---- matvec 2 + residual ----
    {
        float p[8][4];
        #pragma unroll
        for (int a = 0; a < 8; ++a) { p[a][0] = 0.f; p[a][1] = 0.f; p[a][2] = 0.f; p[a][3] = 0.f; }
        #pragma unroll 1
        for (int c = 0; c < 8; ++c) {
            const int h0 = ty * 64 + c * 8;
            float4 wq[8];
            #pragma unroll
            for (int j = 0; j < 8; ++j)
                wq[j] = LDG4(&fw2[(h0 + j) * Ff + f4]);
            #pragma unroll
            for (int a = 0; a < 8; ++a) {
                const float4 a0 = LDG4(&sin_[a][h0]);
                const float4 a1 = LDG4(&sin_[a][h0 + 4]);
                FMA4(p[a], a0.x, wq[0]); FMA4(p[a], a0.y, wq[1]);
                FMA4(p[a], a0.z, wq[2]); FMA4(p[a], a0.w, wq[3]);
                FMA4(p[a], a1.x, wq[4]); FMA4(p[a], a1.y, wq[5]);
                FMA4(p[a], a1.z, wq[6]); FMA4(p[a], a1.w, wq[7]);
            }
        }
        #pragma unroll
        for (int a = 0; a < 8; ++a)
            ST4(&part[ty][a][f4], make_float4(p[a][0], p[a][1], p[a][2], p[a][3]));
    }
    __syncthreads();
    {
        const float fb = fb2[tid];
        #pragma unroll
        for (int a = 0; a < 8; ++a) {
            float o = part[0][a][tid] + part[1][a][tid]
                    + part[2][a][tid] + part[3][a][tid] + fb;
            x[(size_t)(bn0 + a) * Ff + tid] += o;
        }
    }
}

// ---------------------------------------------------------------------------
// k_head: disp/frac/rep, predictor MLP, masked mean, new_cell, new_pos
// ---------------------------------------------------------------------------
__global__ __launch_bounds__(128) void k_head(
    const float* __restrict__ x, const float* __restrict__ pos,
    const float* __restrict__ cell, const float* __restrict__ amask,
    const float* __restrict__ fdw, const float* __restrict__ fdb,
    const float* __restrict__ pw1, const float* __restrict__ pb1,
    const float* __restrict__ pw2, const float* __restrict__ pb2,
    float* __restrict__ out_pos, float* __restrict__ out_cell)
{
    const int b = blockIdx.x;
    const int n = threadIdx.x;

    __shared__ float sinv[9];
    __shared__ float scell[9];
    __shared__ float snc[9];
    __shared__ float sred[Nn][10];

    if (n == 0) {
        float c[9];
        #pragma unroll
        for (int i = 0; i < 9; ++i) { c[i] = cell[b * 9 + i]; scell[i] = c[i]; }
        float det = c[0] * (c[4] * c[8] - c[5] * c[7])
                  - c[1] * (c[3] * c[8] - c[5] * c[6])
                  + c[2] * (c[3] * c[7] - c[4] * c[6]);
        float id = 1.0f / det;
        sinv[0] = (c[4] * c[8] - c[5] * c[7]) * id;
        sinv[1] = (c[2] * c[7] - c[1] * c[8]) * id;
        sinv[2] = (c[1] * c[5] - c[2] * c[4]) * id;
        sinv[3] = (c[5] * c[6] - c[3] * c[8]) * id;
        sinv[4] = (c[0] * c[8] - c[2] * c[6]) * id;
        sinv[5] = (c[2] * c[3] - c[0] * c[5]) * id;
        sinv[6] = (c[3] * c[7] - c[4] * c[6]) * id;
        sinv[7] = (c[1] * c[6] - c[0] * c[7]) * id;
        sinv[8] = (c[0] * c[4] - c[1] * c[3]) * id;
    }
    __syncthreads();

    float xv0 = 0.f, xv1 = 0.f, xv2 = 0.f;
    const int row = (b * Nn + n) * Ff;
    for (int ff = 0; ff < Ff; ++ff) {
        float xr = x[row + ff];
        xv0 = fmaf(xr, fdw[ff * 3 + 0], xv0);
        xv1 = fmaf(xr, fdw[ff * 3 + 1], xv1);
        xv2 = fmaf(xr, fdw[ff * 3 + 2], xv2);
    }
    float fr[3];
    float dsp[3] = {xv0, xv1, xv2};
    const float p0 = pos[(b * Nn + n) * 3 + 0];
    const float p1 = pos[(b * Nn + n) * 3 + 1];
    const float p2 = pos[(b * Nn + n) * 3 + 2];
    #pragma unroll
    for (int j = 0; j < 3; ++j) {
        float z = 10.0f * (dsp[j] + fdb[j]);
        float s = 1.0f / (1.0f + expf(-z));
        float fx = p0 * sinv[0 * 3 + j] + p1 * sinv[1 * 3 + j] + p2 * sinv[2 * 3 + j] + s;
        fr[j] = fx - floorf(fx);
    }

    float rep[3];
    #pragma unroll
    for (int j = 0; j < 3; ++j)
        rep[j] = fr[0] * scell[0 * 3 + j] + fr[1] * scell[1 * 3 + j] + fr[2] * scell[2 * 3 + j];

    float a6[6];
    #pragma unroll
    for (int i = 0; i < 6; ++i) {
        float uv = rep[0] * pw1[0 * 6 + i] + rep[1] * pw1[1 * 6 + i]
                 + rep[2] * pw1[2 * 6 + i] + pb1[i];
        a6[i] = ssp_f(uv);
    }
    float h9[9];
    #pragma unroll
    for (int o = 0; o < 9; ++o) {
        float uv = pb2[o];
        #pragma unroll
        for (int i = 0; i < 6; ++i) uv = fmaf(a6[i], pw2[i * 9 + o], uv);
        h9[o] = uv;
    }

    const float m = amask[b * Nn + n];
    #pragma unroll
    for (int o = 0; o < 9; ++o) sred[n][o] = h9[o] * m;
    sred[n][9] = m;
    __syncthreads();

    for (int s = 64; s >= 1; s >>= 1) {
        if (n < s) {
            #pragma unroll
            for (int o = 0; o < 10; ++o) sred[n][o] += sred[n + s][o];
        }
        __syncthreads();
    }

    if (n < 9) {
        float na = sred[0][9];
        float yo = sred[0][n] / na;
        float scale = 3.0f * powf(na, 1.0f / 3.0f);
        int r = n / 3, c = n - r * 3;
        float v = scale * (((r == c) ? 1.0f : 0.0f) + yo);
        snc[n] = v;
        out_cell[b * 9 + n] = v;
    }
    __syncthreads();

    #pragma unroll
    for (int j = 0; j < 3; ++j) {
        float v = fr[0] * snc[0 * 3 + j] + fr[1] * snc[1 * 3 + j] + fr[2] * snc[2 * 3 + j];
        out_pos[(b * Nn + n) * 3 + j] = v;
    }
}

// ---------------------------------------------------------------------------
extern "C" void kernel_launch(void* const* d_in, const int* in_sizes, int n_in,
                              void* d_out, int out_size, void* d_ws, size_t ws_size,
                              hipStream_t stream)
{
    const float* positions     = (const float*)d_in[0];
    const float* cell          = (const float*)d_in[1];
    const int*   atomic_nums   = (const int*)  d_in[2];
    const int*   neighbors     = (const int*)  d_in[3];
    const float* neighbor_mask = (const float*)d_in[4];
    const float* atom_mask     = (const float*)d_in[5];
    const float* embedding     = (const float*)d_in[6];
    const float* filt_w1       = (const float*)d_in[7];
    const float* filt_b1       = (const float*)d_in[8];
    const float* filt_w2       = (const float*)d_in[9];
    const float* filt_b2       = (const float*)d_in[10];
    const float* in2f_w        = (const float*)d_in[11];
    const float* f2out_w1      = (const float*)d_in[12];
    const float* f2out_b1      = (const float*)d_in[13];
    const float* f2out_w2      = (const float*)d_in[14];
    const float* f2out_b2      = (const float*)d_in[15];
    const float* fd_w          = (const float*)d_in[16];
    const float* fd_b          = (const float*)d_in[17];
    const float* pred_w1       = (const float*)d_in[18];
    const float* pred_b1       = (const float*)d_in[19];
    const float* pred_w2       = (const float*)d_in[20];
    const float* pred_b2       = (const float*)d_in[21];

    float* ws   = (float*)d_ws;
    float* x    = ws;                          // 1048576 f32
    float* y    = x + Bb * Nn * Ff;            // 1048576 f32
    float* agg  = y + Bb * Nn * Ff;            // 1048576 f32
    float* sd   = agg + Bb * Nn * Ff;          // 196608 f32
    float* fcut = sd + Bb * Nn * Kk;           // 196608 f32
    unsigned short* whp  = (unsigned short*)(fcut + Bb * Nn * Kk);
    unsigned short* wlp  = whp + (size_t)Tt * Ff * Ff;
    unsigned short* ihp  = wlp + (size_t)Tt * Ff * Ff;
    unsigned short* ilp  = ihp + (size_t)Tt * Ff * Ff;
    unsigned short* w1hp = ilp + (size_t)Tt * Ff * Ff;
    unsigned short* w1lp = w1hp + (size_t)Tt * Ff * 64;

    float* out_pos  = (float*)d_out;
    float* out_cell = out_pos + Bb * Nn * 3;

    const int BN = Bb * Nn;

    k_setup<<<BN, 256, 0, stream>>>(positions, atomic_nums, neighbors,
                                    neighbor_mask, embedding, x, sd, fcut);
    k_pack256<<<Tt * 128, 64, 0, stream>>>(filt_w2, whp, wlp);
    k_pack256<<<Tt * 128, 64, 0, stream>>>(in2f_w, ihp, ilp);
    k_pack64<<<Tt * 32, 64, 0, stream>>>(filt_w1, w1hp, w1lp);

    for (int t = 0; t < Tt; ++t) {
        k_y16m<<<BN / 16, 512, 0, stream>>>(x,
                                            ihp + (size_t)t * Ff * Ff,
                                            ilp + (size_t)t * Ff * Ff,
                                            y);
        k_aggm3<<<BN, 512, 0, stream>>>(sd, fcut, neighbors, y,
                                        w1hp + (size_t)t * Ff * 64,
                                        w1lp + (size_t)t * Ff * 64,
                                        filt_b1 + (size_t)t * Ff,
                                        whp + (size_t)t * Ff * Ff,
                                        wlp + (size_t)t * Ff * Ff,
                                        filt_b2 + (size_t)t * Ff,
                                        agg);
        k_f2out<<<BN / 8, 256, 0, stream>>>(agg,
                                            f2out_w1 + (size_t)t * Ff * Ff,
                                            f2out_b1 + (size_t)t * Ff,
                                            f2out_w2 + (size_t)t * Ff * Ff,
                                            f2out_b2 + (size_t)t * Ff,
                                            x);
    }

    k_head<<<Bb, 128, 0, stream>>>(x, positions, cell, atom_mask,
                                   fd_w, fd_b, pred_w1, pred_b1, pred_w2, pred_b2,
                                   out_pos, out_cell);
}

// Round 18
// 486.709 us; speedup vs baseline: 1.6477x; 1.6453x over previous
//
#include <hip/hip_runtime.h>
#include <math.h>

#define Bb 32
#define Nn 128
#define Kk 48
#define Ff 256
#define Gg 50
#define Tt 3

typedef __attribute__((ext_vector_type(8))) short bf16x8;
typedef __attribute__((ext_vector_type(4))) float f32x4;

#define MFMA_B16(a, b, c) __builtin_amdgcn_mfma_f32_16x16x32_bf16((a), (b), (c), 0, 0, 0)

// fast ssp: v_exp_f32/v_log_f32 based; |err| ~1e-6, fine vs 0.34 threshold
__device__ __forceinline__ float ssp_f(float v) {
    return fmaxf(v, 0.f) + __logf(1.0f + __expf(-fabsf(v))) - 0.69314718055994530942f;
}

__device__ __forceinline__ unsigned short f2bf(float x) {
    union { float f; unsigned int u; } v; v.f = x;
    unsigned int r = v.u + 0x7FFFu + ((v.u >> 16) & 1u);
    return (unsigned short)(r >> 16);
}
__device__ __forceinline__ float bf2f(unsigned short h) {
    union { unsigned int u; float f; } v; v.u = ((unsigned int)h) << 16;
    return v.f;
}

union BF8 { bf16x8 v; short s[8]; };

#define LDG4(p) (*reinterpret_cast<const float4*>(p))
#define ST4(p, v) (*reinterpret_cast<float4*>(p) = (v))

#define FMA4(dst, s, vv)                      \
    dst[0] = fmaf((s), (vv).x, dst[0]);       \
    dst[1] = fmaf((s), (vv).y, dst[1]);       \
    dst[2] = fmaf((s), (vv).z, dst[2]);       \
    dst[3] = fmaf((s), (vv).w, dst[3]);

// ---------------------------------------------------------------------------
// k_setup: x = embedding[z]; d (raw distance), fcut per (b,n,k)
// ---------------------------------------------------------------------------
__global__ __launch_bounds__(256) void k_setup(
    const float* __restrict__ pos, const int* __restrict__ zz,
    const int* __restrict__ nbr, const float* __restrict__ nmask,
    const float* __restrict__ emb,
    float* __restrict__ x, float* __restrict__ sd_g, float* __restrict__ fcut)
{
    const int bn = blockIdx.x;
    const int b  = bn >> 7;
    const int t  = threadIdx.x;

    x[bn * Ff + t] = emb[zz[bn] * Ff + t];

    if (t < Kk) {
        int j = nbr[bn * Kk + t];
        float px = pos[bn * 3 + 0], py = pos[bn * 3 + 1], pz = pos[bn * 3 + 2];
        int rj = (b * Nn + j) * 3;
        float dx = pos[rj + 0] - px;
        float dy = pos[rj + 1] - py;
        float dz = pos[rj + 2] - pz;
        float d = sqrtf(fmaf(dx, dx, fmaf(dy, dy, dz * dz)) + 1e-8f);
        sd_g[bn * Kk + t] = d;
        float fc = 0.5f * (cosf(3.14159265358979323846f * d / 5.0f) + 1.0f);
        fc = (d < 5.0f) ? fc : 0.0f;
        fcut[bn * Kk + t] = fc * nmask[bn * Kk + t];
    }
}

// ---------------------------------------------------------------------------
// k_pack256: [t][256][256] f32 -> split bf16, MFMA-B-fragment-major
// ---------------------------------------------------------------------------
__global__ __launch_bounds__(64) void k_pack256(
    const float* __restrict__ src,
    unsigned short* __restrict__ dh, unsigned short* __restrict__ dl)
{
    const int blk  = blockIdx.x;       // t*128 + nt16*8 + kk
    const int t    = blk >> 7;
    const int rem  = blk & 127;
    const int nt16 = rem >> 3;
    const int kk   = rem & 7;
    const int a    = threadIdx.x;
    const int n    = nt16 * 16 + (a & 15);
    const int kb   = kk * 32 + (a >> 4) * 8;
    const size_t dst0 = (((size_t)t * 128 + rem) * 64 + a) * 8;
    #pragma unroll
    for (int i = 0; i < 8; ++i) {
        float v = src[(size_t)t * Ff * Ff + (size_t)(kb + i) * Ff + n];
        unsigned short hi = f2bf(v);
        dh[dst0 + i] = hi;
        dl[dst0 + i] = f2bf(v - bf2f(hi));
    }
}

// ---------------------------------------------------------------------------
// k_pack64: w1 [t][50][256] -> split bf16 fragment-major, K padded to 64
// ---------------------------------------------------------------------------
__global__ __launch_bounds__(64) void k_pack64(
    const float* __restrict__ src,
    unsigned short* __restrict__ dh, unsigned short* __restrict__ dl)
{
    const int blk  = blockIdx.x;       // t*32 + nt16*2 + kk
    const int t    = blk >> 5;
    const int rem  = blk & 31;
    const int nt16 = rem >> 1;
    const int kk   = rem & 1;
    const int a    = threadIdx.x;
    const int n    = nt16 * 16 + (a & 15);
    const int kb   = kk * 32 + (a >> 4) * 8;
    const size_t dst0 = (((size_t)t * 32 + rem) * 64 + a) * 8;
    #pragma unroll
    for (int i = 0; i < 8; ++i) {
        const int k = kb + i;
        float v = (k < Gg) ? src[(size_t)t * Gg * Ff + (size_t)k * Ff + n] : 0.f;
        unsigned short hi = f2bf(v);
        dh[dst0 + i] = hi;
        dl[dst0 + i] = f2bf(v - bf2f(hi));
    }
}

// ---------------------------------------------------------------------------
// k_y16m: y = x @ in2f_w[t], 16 atoms/block, 512 thr = 8 waves
// ---------------------------------------------------------------------------
__global__ __launch_bounds__(512) void k_y16m(
    const float* __restrict__ x,
    const unsigned short* __restrict__ bhp, const unsigned short* __restrict__ blp,
    float* __restrict__ y)
{
    const int bn0  = blockIdx.x * 16;
    const int tid  = threadIdx.x;
    const int w    = tid >> 6;
    const int lane = tid & 63;
    const int lq   = lane >> 4;
    const int arow = lane & 15;

    f32x4 acc0 = (f32x4){0.f, 0.f, 0.f, 0.f};
    f32x4 acc1 = (f32x4){0.f, 0.f, 0.f, 0.f};
    const float* xrow = x + (size_t)(bn0 + arow) * Ff;

    #pragma unroll 1
    for (int kk = 0; kk < 8; ++kk) {
        const int ko = kk * 32 + lq * 8;
        const float4 a0 = LDG4(&xrow[ko]);
        const float4 a1 = LDG4(&xrow[ko + 4]);
        float av[8] = {a0.x, a0.y, a0.z, a0.w, a1.x, a1.y, a1.z, a1.w};
        BF8 ah, al;
        #pragma unroll
        for (int i = 0; i < 8; ++i) {
            unsigned short h = f2bf(av[i]);
            ah.s[i] = (short)h;
            al.s[i] = (short)f2bf(av[i] - bf2f(h));
        }
        #pragma unroll
        for (int nt = 0; nt < 2; ++nt) {
            const size_t off = ((size_t)((2 * w + nt) * 8 + kk) * 64 + lane) * 8;
            bf16x8 bh = *reinterpret_cast<const bf16x8*>(bhp + off);
            bf16x8 bl = *reinterpret_cast<const bf16x8*>(blp + off);
            f32x4& ac = nt ? acc1 : acc0;
            ac = MFMA_B16(ah.v, bh, ac);
            ac = MFMA_B16(ah.v, bl, ac);
            ac = MFMA_B16(al.v, bh, ac);
        }
    }
    #pragma unroll
    for (int j = 0; j < 4; ++j) {
        y[(size_t)(bn0 + lq * 4 + j) * Ff + w * 32 + arow]      = acc0[j];
        y[(size_t)(bn0 + lq * 4 + j) * Ff + w * 32 + 16 + arow] = acc1[j];
    }
}

// ---------------------------------------------------------------------------
// k_aggm4: TWO atoms per block, 512 thr = 8 waves, fused per-m-tile pipeline:
// for each of 3 m-tiles (16 k-rows): {layer1 MFMA both atoms (fexp in-reg,
// fast exp) -> ssp -> split -> H-tile to LDS (A-frag-major) -> barrier ->
// layer2 MFMA both atoms (B-frag shared) -> consume -> barrier}.
// LDS 32 KB -> 4 blocks/CU (wave-slot cap). B (w2) read 3x/block but
// shared by 2 atoms.
// ---------------------------------------------------------------------------
__global__ __launch_bounds__(512) void k_aggm4(
    const float* __restrict__ sd, const float* __restrict__ fcut,
    const int* __restrict__ nbr, const float* __restrict__ y,
    const unsigned short* __restrict__ w1hp, const unsigned short* __restrict__ w1lp,
    const float* __restrict__ b1,
    const unsigned short* __restrict__ whp, const unsigned short* __restrict__ wlp,
    const float* __restrict__ b2,
    float* __restrict__ agg)
{
    const int bn0   = blockIdx.x * 2;
    const int bbase = (bn0 >> 7) << 7;       // b * 128
    const int tid   = threadIdx.x;
    const int w     = tid >> 6;
    const int lane  = tid & 63;
    const int lq    = lane >> 4;
    const int arow  = lane & 15;

    __shared__ __align__(16) unsigned short HhP[2][8 * 64 * 8];  // 16384 B
    __shared__ __align__(16) unsigned short HlP[2][8 * 64 * 8];  // 16384 B
    __shared__ float scut[2][Kk];
    __shared__ int   snbr[2][Kk];

    if (tid < 96) {
        const int a = tid / 48, k = tid - (tid / 48) * 48;
        scut[a][k] = fcut[(bn0 + a) * Kk + k];
        snbr[a][k] = nbr[(bn0 + a) * Kk + k];
    }

    const float step = 5.0f / 49.0f;
    const float coeff = -0.5f / (step * step);
    const float b1v = b1[w * 32 + arow];          // col for nt=0
    const float b1v2 = b1[w * 32 + 16 + arow];    // col for nt=1
    const float b2v0 = b2[w * 32 + arow];
    const float b2v1 = b2[w * 32 + 16 + arow];

    float aggp[2][2] = {{0.f, 0.f}, {0.f, 0.f}};

    #pragma unroll 1
    for (int mt = 0; mt < 3; ++mt) {
        // ============ layer 1 (MFMA) for both atoms -> H-tile to LDS ========
        #pragma unroll
        for (int a = 0; a < 2; ++a) {
            const float d = sd[(bn0 + a) * Kk + mt * 16 + arow];

            BF8 fah[2], fal[2];
            #pragma unroll
            for (int kk = 0; kk < 2; ++kk) {
                #pragma unroll
                for (int i = 0; i < 8; ++i) {
                    const int g = kk * 32 + lq * 8 + i;
                    float dd = d - step * (float)g;
                    float val = (g < Gg) ? __expf(coeff * dd * dd) : 0.f;
                    unsigned short h = f2bf(val);
                    fah[kk].s[i] = (short)h;
                    fal[kk].s[i] = (short)f2bf(val - bf2f(h));
                }
            }

            f32x4 acc1[2];
            acc1[0] = (f32x4){0.f, 0.f, 0.f, 0.f};
            acc1[1] = (f32x4){0.f, 0.f, 0.f, 0.f};

            #pragma unroll
            for (int kk = 0; kk < 2; ++kk) {
                #pragma unroll
                for (int nt = 0; nt < 2; ++nt) {
                    const size_t off = ((size_t)((2 * w + nt) * 2 + kk) * 64 + lane) * 8;
                    bf16x8 bh = *reinterpret_cast<const bf16x8*>(w1hp + off);
                    bf16x8 bl = *reinterpret_cast<const bf16x8*>(w1lp + off);
                    acc1[nt] = MFMA_B16(fah[kk].v, bh, acc1[nt]);
                    acc1[nt] = MFMA_B16(fah[kk].v, bl, acc1[nt]);
                    acc1[nt] = MFMA_B16(fal[kk].v, bh, acc1[nt]);
                }
            }

            // D(row=lq*4+j, col=w*32+nt*16+arow) -> ssp -> split ->
            // A-fragment-major within this m-tile: kk2 = w, frag lane fl
            #pragma unroll
            for (int nt = 0; nt < 2; ++nt) {
                const float bb = nt ? b1v2 : b1v;
                const int a_ = (nt * 2 + (arow >> 3)) << 4;
                const int i_ = arow & 7;
                #pragma unroll
                for (int j = 0; j < 4; ++j) {
                    float v = ssp_f(acc1[nt][j] + bb);
                    unsigned short hh = f2bf(v);
                    unsigned short ll = f2bf(v - bf2f(hh));
                    const int fl = (lq * 4 + j) | a_;
                    const int idx = (w * 64 + fl) * 8 + i_;
                    HhP[a][idx] = hh;
                    HlP[a][idx] = ll;
                }
            }
        }
        __syncthreads();

        // ============ layer 2 (MFMA): B-frags shared across both atoms ======
        f32x4 acc2[2][2];
        #pragma unroll
        for (int a = 0; a < 2; ++a) {
            acc2[a][0] = (f32x4){0.f, 0.f, 0.f, 0.f};
            acc2[a][1] = (f32x4){0.f, 0.f, 0.f, 0.f};
        }

        #pragma unroll 1
        for (int kk = 0; kk < 8; ++kk) {
            bf16x8 bh[2], bl[2];
            #pragma unroll
            for (int nt = 0; nt < 2; ++nt) {
                const size_t off = ((size_t)((2 * w + nt) * 8 + kk) * 64 + lane) * 8;
                bh[nt] = *reinterpret_cast<const bf16x8*>(whp + off);
                bl[nt] = *reinterpret_cast<const bf16x8*>(wlp + off);
            }
            const int abase = (kk * 64 + lane) * 8;
            #pragma unroll
            for (int a = 0; a < 2; ++a) {
                bf16x8 ah = *reinterpret_cast<const bf16x8*>(&HhP[a][abase]);
                bf16x8 al = *reinterpret_cast<const bf16x8*>(&HlP[a][abase]);
                #pragma unroll
                for (int nt = 0; nt < 2; ++nt) {
                    acc2[a][nt] = MFMA_B16(ah, bh[nt], acc2[a][nt]);
                    acc2[a][nt] = MFMA_B16(ah, bl[nt], acc2[a][nt]);
                    acc2[a][nt] = MFMA_B16(al, bh[nt], acc2[a][nt]);
                }
            }
        }

        // ============ consume this m-tile: cutoff + neighbor y gather ========
        #pragma unroll
        for (int a = 0; a < 2; ++a) {
            #pragma unroll
            for (int j = 0; j < 4; ++j) {
                const int r = mt * 16 + lq * 4 + j;
                const float ct = scut[a][r];
                const int   nb = snbr[a][r];
                const float* yr = y + (size_t)(bbase + nb) * Ff + w * 32 + arow;
                aggp[a][0] = fmaf((acc2[a][0][j] + b2v0) * ct, yr[0],  aggp[a][0]);
                aggp[a][1] = fmaf((acc2[a][1][j] + b2v1) * ct, yr[16], aggp[a][1]);
            }
        }
        __syncthreads();   // H-tile consumed; next mt may overwrite
    }

    // ---- reduce across lq, write agg for both atoms ----
    #pragma unroll
    for (int a = 0; a < 2; ++a) {
        #pragma unroll
        for (int nt = 0; nt < 2; ++nt) {
            aggp[a][nt] += __shfl_xor(aggp[a][nt], 16);
            aggp[a][nt] += __shfl_xor(aggp[a][nt], 32);
        }
        if (lq == 0) {
            agg[(size_t)(bn0 + a) * Ff + w * 32 + arow]      = aggp[a][0];
            agg[(size_t)(bn0 + a) * Ff + w * 32 + 16 + arow] = aggp[a][1];
        }
    }
}

// ---------------------------------------------------------------------------
// k_f2out: x += ssp(agg@fw1+fb1)@fw2+fb2, 8 atoms per block (VALU)
// ---------------------------------------------------------------------------
__global__ __launch_bounds__(256) void k_f2out(
    const float* __restrict__ agg,
    const float* __restrict__ fw1, const float* __restrict__ fb1,
    const float* __restrict__ fw2, const float* __restrict__ fb2,
    float* __restrict__ x)
{
    const int bn0 = blockIdx.x * 8;
    const int tid = threadIdx.x;
    const int tx  = tid & 63;
    const int ty  = tid >> 6;
    const int f4  = tx * 4;

    __shared__ __align__(16) float sin_[8][Ff];     // 8 KB (agg, then sv)
    __shared__ __align__(16) float part[4][8][Ff];  // 32 KB

    #pragma unroll
    for (int a = 0; a < 8; ++a)
        sin_[a][tid] = agg[(size_t)(bn0 + a) * Ff + tid];
    __syncthreads();

    {
        float p[8][4];
        #pragma unroll
        for (int a = 0; a < 8; ++a) { p[a][0] = 0.f; p[a][1] = 0.f; p[a][2] = 0.f; p[a][3] = 0.f; }
        #pragma unroll 1
        for (int c = 0; c < 8; ++c) {
            const int h0 = ty * 64 + c * 8;
            float4 wq[8];
            #pragma unroll
            for (int j = 0; j < 8; ++j)
                wq[j] = LDG4(&fw1[(h0 + j) * Ff + f4]);
            #pragma unroll
            for (int a = 0; a < 8; ++a) {
                const float4 a0 = LDG4(&sin_[a][h0]);
                const float4 a1 = LDG4(&sin_[a][h0 + 4]);
                FMA4(p[a], a0.x, wq[0]); FMA4(p[a], a0.y, wq[1]);
                FMA4(p[a], a0.z, wq[2]); FMA4(p[a], a0.w, wq[3]);
                FMA4(p[a], a1.x, wq[4]); FMA4(p[a], a1.y, wq[5]);
                FMA4(p[a], a1.z, wq[6]); FMA4(p[a], a1.w, wq[7]);
            }
        }
        #pragma unroll
        for (int a = 0; a < 8; ++a)
            ST4(&part[ty][a][f4], make_float4(p[a][0], p[a][1], p[a][2], p[a][3]));
    }
    __syncthreads();
    {
        const float fb = fb1[tid];
        #pragma unroll
        for (int a = 0; a < 8; ++a) {
            float u = part[0][a][tid] + part[1][a][tid]
                    + part[2][a][tid] + part[3][a][tid] + fb;
            sin_[a][tid] = ssp_f(u);
        }
    }
    __syncthreads();

    {
        float p[8][4];
        #pragma unroll
        for (int a = 0; a < 8; ++a) { p[a][0] = 0.f; p[a][1] = 0.f; p[a][2] = 0.f; p[a][3] = 0.f; }
        #pragma unroll 1
        for (int c = 0; c < 8; ++c) {
            const int h0 = ty * 64 + c * 8;
            float4 wq[8];
            #pragma unroll
            for (int j = 0; j < 8; ++j)
                wq[j] = LDG4(&fw2[(h0 + j) * Ff + f4]);
            #pragma unroll
            for (int a = 0; a < 8; ++a) {
                const float4 a0 = LDG4(&sin_[a][h0]);
                const float4 a1 = LDG4(&sin_[a][h0 + 4]);
                FMA4(p[a], a0.x, wq[0]); FMA4(p[a], a0.y, wq[1]);
                FMA4(p[a], a0.z, wq[2]); FMA4(p[a], a0.w, wq[3]);
                FMA4(p[a], a1.x, wq[4]); FMA4(p[a], a1.y, wq[5]);
                FMA4(p[a], a1.z, wq[6]); FMA4(p[a], a1.w, wq[7]);
            }
        }
        #pragma unroll
        for (int a = 0; a < 8; ++a)
            ST4(&part[ty][a][f4], make_float4(p[a][0], p[a][1], p[a][2], p[a][3]));
    }
    __syncthreads();
    {
        const float fb = fb2[tid];
        #pragma unroll
        for (int a = 0; a < 8; ++a) {
            float o = part[0][a][tid] + part[1][a][tid]
                    + part[2][a][tid] + part[3][a][tid] + fb;
            x[(size_t)(bn0 + a) * Ff + tid] += o;
        }
    }
}

// ---------------------------------------------------------------------------
// k_head: disp/frac/rep, predictor MLP, masked mean, new_cell, new_pos
// ---------------------------------------------------------------------------
__global__ __launch_bounds__(128) void k_head(
    const float* __restrict__ x, const float* __restrict__ pos,
    const float* __restrict__ cell, const float* __restrict__ amask,
    const float* __restrict__ fdw, const float* __restrict__ fdb,
    const float* __restrict__ pw1, const float* __restrict__ pb1,
    const float* __restrict__ pw2, const float* __restrict__ pb2,
    float* __restrict__ out_pos, float* __restrict__ out_cell)
{
    const int b = blockIdx.x;
    const int n = threadIdx.x;

    __shared__ float sinv[9];
    __shared__ float scell[9];
    __shared__ float snc[9];
    __shared__ float sred[Nn][10];

    if (n == 0) {
        float c[9];
        #pragma unroll
        for (int i = 0; i < 9; ++i) { c[i] = cell[b * 9 + i]; scell[i] = c[i]; }
        float det = c[0] * (c[4] * c[8] - c[5] * c[7])
                  - c[1] * (c[3] * c[8] - c[5] * c[6])
                  + c[2] * (c[3] * c[7] - c[4] * c[6]);
        float id = 1.0f / det;
        sinv[0] = (c[4] * c[8] - c[5] * c[7]) * id;
        sinv[1] = (c[2] * c[7] - c[1] * c[8]) * id;
        sinv[2] = (c[1] * c[5] - c[2] * c[4]) * id;
        sinv[3] = (c[5] * c[6] - c[3] * c[8]) * id;
        sinv[4] = (c[0] * c[8] - c[2] * c[6]) * id;
        sinv[5] = (c[2] * c[3] - c[0] * c[5]) * id;
        sinv[6] = (c[3] * c[7] - c[4] * c[6]) * id;
        sinv[7] = (c[1] * c[6] - c[0] * c[7]) * id;
        sinv[8] = (c[0] * c[4] - c[1] * c[3]) * id;
    }
    __syncthreads();

    float xv0 = 0.f, xv1 = 0.f, xv2 = 0.f;
    const int row = (b * Nn + n) * Ff;
    for (int ff = 0; ff < Ff; ++ff) {
        float xr = x[row + ff];
        xv0 = fmaf(xr, fdw[ff * 3 + 0], xv0);
        xv1 = fmaf(xr, fdw[ff * 3 + 1], xv1);
        xv2 = fmaf(xr, fdw[ff * 3 + 2], xv2);
    }
    float fr[3];
    float dsp[3] = {xv0, xv1, xv2};
    const float p0 = pos[(b * Nn + n) * 3 + 0];
    const float p1 = pos[(b * Nn + n) * 3 + 1];
    const float p2 = pos[(b * Nn + n) * 3 + 2];
    #pragma unroll
    for (int j = 0; j < 3; ++j) {
        float z = 10.0f * (dsp[j] + fdb[j]);
        float s = 1.0f / (1.0f + expf(-z));
        float fx = p0 * sinv[0 * 3 + j] + p1 * sinv[1 * 3 + j] + p2 * sinv[2 * 3 + j] + s;
        fr[j] = fx - floorf(fx);
    }

    float rep[3];
    #pragma unroll
    for (int j = 0; j < 3; ++j)
        rep[j] = fr[0] * scell[0 * 3 + j] + fr[1] * scell[1 * 3 + j] + fr[2] * scell[2 * 3 + j];

    float a6[6];
    #pragma unroll
    for (int i = 0; i < 6; ++i) {
        float uv = rep[0] * pw1[0 * 6 + i] + rep[1] * pw1[1 * 6 + i]
                 + rep[2] * pw1[2 * 6 + i] + pb1[i];
        a6[i] = ssp_f(uv);
    }
    float h9[9];
    #pragma unroll
    for (int o = 0; o < 9; ++o) {
        float uv = pb2[o];
        #pragma unroll
        for (int i = 0; i < 6; ++i) uv = fmaf(a6[i], pw2[i * 9 + o], uv);
        h9[o] = uv;
    }

    const float m = amask[b * Nn + n];
    #pragma unroll
    for (int o = 0; o < 9; ++o) sred[n][o] = h9[o] * m;
    sred[n][9] = m;
    __syncthreads();

    for (int s = 64; s >= 1; s >>= 1) {
        if (n < s) {
            #pragma unroll
            for (int o = 0; o < 10; ++o) sred[n][o] += sred[n + s][o];
        }
        __syncthreads();
    }

    if (n < 9) {
        float na = sred[0][9];
        float yo = sred[0][n] / na;
        float scale = 3.0f * powf(na, 1.0f / 3.0f);
        int r = n / 3, c = n - r * 3;
        float v = scale * (((r == c) ? 1.0f : 0.0f) + yo);
        snc[n] = v;
        out_cell[b * 9 + n] = v;
    }
    __syncthreads();

    #pragma unroll
    for (int j = 0; j < 3; ++j) {
        float v = fr[0] * snc[0 * 3 + j] + fr[1] * snc[1 * 3 + j] + fr[2] * snc[2 * 3 + j];
        out_pos[(b * Nn + n) * 3 + j] = v;
    }
}

// ---------------------------------------------------------------------------
extern "C" void kernel_launch(void* const* d_in, const int* in_sizes, int n_in,
                              void* d_out, int out_size, void* d_ws, size_t ws_size,
                              hipStream_t stream)
{
    const float* positions     = (const float*)d_in[0];
    const float* cell          = (const float*)d_in[1];
    const int*   atomic_nums   = (const int*)  d_in[2];
    const int*   neighbors     = (const int*)  d_in[3];
    const float* neighbor_mask = (const float*)d_in[4];
    const float* atom_mask     = (const float*)d_in[5];
    const float* embedding     = (const float*)d_in[6];
    const float* filt_w1       = (const float*)d_in[7];
    const float* filt_b1       = (const float*)d_in[8];
    const float* filt_w2       = (const float*)d_in[9];
    const float* filt_b2       = (const float*)d_in[10];
    const float* in2f_w        = (const float*)d_in[11];
    const float* f2out_w1      = (const float*)d_in[12];
    const float* f2out_b1      = (const float*)d_in[13];
    const float* f2out_w2      = (const float*)d_in[14];
    const float* f2out_b2      = (const float*)d_in[15];
    const float* fd_w          = (const float*)d_in[16];
    const float* fd_b          = (const float*)d_in[17];
    const float* pred_w1       = (const float*)d_in[18];
    const float* pred_b1       = (const float*)d_in[19];
    const float* pred_w2       = (const float*)d_in[20];
    const float* pred_b2       = (const float*)d_in[21];

    float* ws   = (float*)d_ws;
    float* x    = ws;                          // 1048576 f32
    float* y    = x + Bb * Nn * Ff;            // 1048576 f32
    float* agg  = y + Bb * Nn * Ff;            // 1048576 f32
    float* sd   = agg + Bb * Nn * Ff;          // 196608 f32
    float* fcut = sd + Bb * Nn * Kk;           // 196608 f32
    unsigned short* whp  = (unsigned short*)(fcut + Bb * Nn * Kk);
    unsigned short* wlp  = whp + (size_t)Tt * Ff * Ff;
    unsigned short* ihp  = wlp + (size_t)Tt * Ff * Ff;
    unsigned short* ilp  = ihp + (size_t)Tt * Ff * Ff;
    unsigned short* w1hp = ilp + (size_t)Tt * Ff * Ff;
    unsigned short* w1lp = w1hp + (size_t)Tt * Ff * 64;

    float* out_pos  = (float*)d_out;
    float* out_cell = out_pos + Bb * Nn * 3;

    const int BN = Bb * Nn;

    k_setup<<<BN, 256, 0, stream>>>(positions, atomic_nums, neighbors,
                                    neighbor_mask, embedding, x, sd, fcut);
    k_pack256<<<Tt * 128, 64, 0, stream>>>(filt_w2, whp, wlp);
    k_pack256<<<Tt * 128, 64, 0, stream>>>(in2f_w, ihp, ilp);
    k_pack64<<<Tt * 32, 64, 0, stream>>>(filt_w1, w1hp, w1lp);

    for (int t = 0; t < Tt; ++t) {
        k_y16m<<<BN / 16, 512, 0, stream>>>(x,
                                            ihp + (size_t)t * Ff * Ff,
                                            ilp + (size_t)t * Ff * Ff,
                                            y);
        k_aggm4<<<BN / 2, 512, 0, stream>>>(sd, fcut, neighbors, y,
                                            w1hp + (size_t)t * Ff * 64,
                                            w1lp + (size_t)t * Ff * 64,
                                            filt_b1 + (size_t)t * Ff,
                                            whp + (size_t)t * Ff * Ff,
                                            wlp + (size_t)t * Ff * Ff,
                                            filt_b2 + (size_t)t * Ff,
                                            agg);
        k_f2out<<<BN / 8, 256, 0, stream>>>(agg,
                                            f2out_w1 + (size_t)t * Ff * Ff,
                                            f2out_b1 + (size_t)t * Ff,
                                            f2out_w2 + (size_t)t * Ff * Ff,
                                            f2out_b2 + (size_t)t * Ff,
                                            x);
    }

    k_head<<<Bb, 128, 0, stream>>>(x, positions, cell, atom_mask,
                                   fd_w, fd_b, pred_w1, pred_b1, pred_w2, pred_b2,
                                   out_pos, out_cell);
}

// Round 19
// 427.441 us; speedup vs baseline: 1.8762x; 1.1387x over previous
//
#include <hip/hip_runtime.h>
#include <math.h>

#define Bb 32
#define Nn 128
#define Kk 48
#define Ff 256
#define Gg 50
#define Tt 3

typedef __attribute__((ext_vector_type(8))) short bf16x8;
typedef __attribute__((ext_vector_type(4))) float f32x4;

#define MFMA_B16(a, b, c) __builtin_amdgcn_mfma_f32_16x16x32_bf16((a), (b), (c), 0, 0, 0)

// fast ssp: v_exp_f32/v_log_f32 based; |err| ~1e-6, fine vs 0.34 threshold
__device__ __forceinline__ float ssp_f(float v) {
    return fmaxf(v, 0.f) + __logf(1.0f + __expf(-fabsf(v))) - 0.69314718055994530942f;
}

__device__ __forceinline__ unsigned short f2bf(float x) {
    union { float f; unsigned int u; } v; v.f = x;
    unsigned int r = v.u + 0x7FFFu + ((v.u >> 16) & 1u);
    return (unsigned short)(r >> 16);
}
__device__ __forceinline__ float bf2f(unsigned short h) {
    union { unsigned int u; float f; } v; v.u = ((unsigned int)h) << 16;
    return v.f;
}

union BF8 { bf16x8 v; short s[8]; };

#define LDG4(p) (*reinterpret_cast<const float4*>(p))
#define ST4(p, v) (*reinterpret_cast<float4*>(p) = (v))

#define FMA4(dst, s, vv)                      \
    dst[0] = fmaf((s), (vv).x, dst[0]);       \
    dst[1] = fmaf((s), (vv).y, dst[1]);       \
    dst[2] = fmaf((s), (vv).z, dst[2]);       \
    dst[3] = fmaf((s), (vv).w, dst[3]);

// ---------------------------------------------------------------------------
// k_setup: x = embedding[z]; d (raw distance), fcut per (b,n,k)
// ---------------------------------------------------------------------------
__global__ __launch_bounds__(256) void k_setup(
    const float* __restrict__ pos, const int* __restrict__ zz,
    const int* __restrict__ nbr, const float* __restrict__ nmask,
    const float* __restrict__ emb,
    float* __restrict__ x, float* __restrict__ sd_g, float* __restrict__ fcut)
{
    const int bn = blockIdx.x;
    const int b  = bn >> 7;
    const int t  = threadIdx.x;

    x[bn * Ff + t] = emb[zz[bn] * Ff + t];

    if (t < Kk) {
        int j = nbr[bn * Kk + t];
        float px = pos[bn * 3 + 0], py = pos[bn * 3 + 1], pz = pos[bn * 3 + 2];
        int rj = (b * Nn + j) * 3;
        float dx = pos[rj + 0] - px;
        float dy = pos[rj + 1] - py;
        float dz = pos[rj + 2] - pz;
        float d = sqrtf(fmaf(dx, dx, fmaf(dy, dy, dz * dz)) + 1e-8f);
        sd_g[bn * Kk + t] = d;
        float fc = 0.5f * (cosf(3.14159265358979323846f * d / 5.0f) + 1.0f);
        fc = (d < 5.0f) ? fc : 0.0f;
        fcut[bn * Kk + t] = fc * nmask[bn * Kk + t];
    }
}

// ---------------------------------------------------------------------------
// k_packfe: fexp A-fragments (split bf16), fragment-major, ONCE for all t.
// Layout: [bn][mt*2+kk][lane][8]; lane=(lq,arow): row=arow(k), g=kk*32+lq*8+i.
// grid: BN blocks x 384 thr (6 waves; wave w -> tile mt=w>>1, kk=w&1).
// ---------------------------------------------------------------------------
__global__ __launch_bounds__(384) void k_packfe(
    const float* __restrict__ sd,
    unsigned short* __restrict__ feh, unsigned short* __restrict__ fel)
{
    const int bn   = blockIdx.x;
    const int tid  = threadIdx.x;
    const int w    = tid >> 6;          // 0..5
    const int lane = tid & 63;
    const int lq   = lane >> 4;
    const int arow = lane & 15;
    const int mt   = w >> 1;
    const int kk   = w & 1;

    const float step = 5.0f / 49.0f;
    const float coeff = -0.5f / (step * step);
    const float d = sd[bn * Kk + mt * 16 + arow];

    BF8 ah, al;
    #pragma unroll
    for (int i = 0; i < 8; ++i) {
        const int g = kk * 32 + lq * 8 + i;
        float dd = d - step * (float)g;
        float val = (g < Gg) ? __expf(coeff * dd * dd) : 0.f;
        unsigned short h = f2bf(val);
        ah.s[i] = (short)h;
        al.s[i] = (short)f2bf(val - bf2f(h));
    }
    const size_t off = (((size_t)bn * 6 + w) * 64 + lane) * 8;
    *reinterpret_cast<bf16x8*>(feh + off) = ah.v;
    *reinterpret_cast<bf16x8*>(fel + off) = al.v;
}

// ---------------------------------------------------------------------------
// k_pack256: [t][256][256] f32 -> split bf16, MFMA-B-fragment-major
// ---------------------------------------------------------------------------
__global__ __launch_bounds__(64) void k_pack256(
    const float* __restrict__ src,
    unsigned short* __restrict__ dh, unsigned short* __restrict__ dl)
{
    const int blk  = blockIdx.x;       // t*128 + nt16*8 + kk
    const int t    = blk >> 7;
    const int rem  = blk & 127;
    const int nt16 = rem >> 3;
    const int kk   = rem & 7;
    const int a    = threadIdx.x;
    const int n    = nt16 * 16 + (a & 15);
    const int kb   = kk * 32 + (a >> 4) * 8;
    const size_t dst0 = (((size_t)t * 128 + rem) * 64 + a) * 8;
    #pragma unroll
    for (int i = 0; i < 8; ++i) {
        float v = src[(size_t)t * Ff * Ff + (size_t)(kb + i) * Ff + n];
        unsigned short hi = f2bf(v);
        dh[dst0 + i] = hi;
        dl[dst0 + i] = f2bf(v - bf2f(hi));
    }
}

// ---------------------------------------------------------------------------
// k_pack64: w1 [t][50][256] -> split bf16 fragment-major, K padded to 64
// ---------------------------------------------------------------------------
__global__ __launch_bounds__(64) void k_pack64(
    const float* __restrict__ src,
    unsigned short* __restrict__ dh, unsigned short* __restrict__ dl)
{
    const int blk  = blockIdx.x;       // t*32 + nt16*2 + kk
    const int t    = blk >> 5;
    const int rem  = blk & 31;
    const int nt16 = rem >> 1;
    const int kk   = rem & 1;
    const int a    = threadIdx.x;
    const int n    = nt16 * 16 + (a & 15);
    const int kb   = kk * 32 + (a >> 4) * 8;
    const size_t dst0 = (((size_t)t * 32 + rem) * 64 + a) * 8;
    #pragma unroll
    for (int i = 0; i < 8; ++i) {
        const int k = kb + i;
        float v = (k < Gg) ? src[(size_t)t * Gg * Ff + (size_t)k * Ff + n] : 0.f;
        unsigned short hi = f2bf(v);
        dh[dst0 + i] = hi;
        dl[dst0 + i] = f2bf(v - bf2f(hi));
    }
}

// ---------------------------------------------------------------------------
// k_y16m: y = x @ in2f_w[t], 16 atoms/block, 512 thr = 8 waves
// ---------------------------------------------------------------------------
__global__ __launch_bounds__(512) void k_y16m(
    const float* __restrict__ x,
    const unsigned short* __restrict__ bhp, const unsigned short* __restrict__ blp,
    float* __restrict__ y)
{
    const int bn0  = blockIdx.x * 16;
    const int tid  = threadIdx.x;
    const int w    = tid >> 6;
    const int lane = tid & 63;
    const int lq   = lane >> 4;
    const int arow = lane & 15;

    f32x4 acc0 = (f32x4){0.f, 0.f, 0.f, 0.f};
    f32x4 acc1 = (f32x4){0.f, 0.f, 0.f, 0.f};
    const float* xrow = x + (size_t)(bn0 + arow) * Ff;

    #pragma unroll 1
    for (int kk = 0; kk < 8; ++kk) {
        const int ko = kk * 32 + lq * 8;
        const float4 a0 = LDG4(&xrow[ko]);
        const float4 a1 = LDG4(&xrow[ko + 4]);
        float av[8] = {a0.x, a0.y, a0.z, a0.w, a1.x, a1.y, a1.z, a1.w};
        BF8 ah, al;
        #pragma unroll
        for (int i = 0; i < 8; ++i) {
            unsigned short h = f2bf(av[i]);
            ah.s[i] = (short)h;
            al.s[i] = (short)f2bf(av[i] - bf2f(h));
        }
        #pragma unroll
        for (int nt = 0; nt < 2; ++nt) {
            const size_t off = ((size_t)((2 * w + nt) * 8 + kk) * 64 + lane) * 8;
            bf16x8 bh = *reinterpret_cast<const bf16x8*>(bhp + off);
            bf16x8 bl = *reinterpret_cast<const bf16x8*>(blp + off);
            f32x4& ac = nt ? acc1 : acc0;
            ac = MFMA_B16(ah.v, bh, ac);
            ac = MFMA_B16(ah.v, bl, ac);
            ac = MFMA_B16(al.v, bh, ac);
        }
    }
    #pragma unroll
    for (int j = 0; j < 4; ++j) {
        y[(size_t)(bn0 + lq * 4 + j) * Ff + w * 32 + arow]      = acc0[j];
        y[(size_t)(bn0 + lq * 4 + j) * Ff + w * 32 + 16 + arow] = acc1[j];
    }
}

// ---------------------------------------------------------------------------
// k_aggm4b: TWO atoms per block, 512 thr = 8 waves, per-m-tile fused pipeline.
// fexp A-fragments PRELOADED from k_packfe (coalesced 16B/lane) — no exp,
// no split in the hot loop. LDS 32 KB.
// ---------------------------------------------------------------------------
__global__ __launch_bounds__(512) void k_aggm4b(
    const float* __restrict__ fcut,
    const int* __restrict__ nbr, const float* __restrict__ y,
    const unsigned short* __restrict__ feh, const unsigned short* __restrict__ fel,
    const unsigned short* __restrict__ w1hp, const unsigned short* __restrict__ w1lp,
    const float* __restrict__ b1,
    const unsigned short* __restrict__ whp, const unsigned short* __restrict__ wlp,
    const float* __restrict__ b2,
    float* __restrict__ agg)
{
    const int bn0   = blockIdx.x * 2;
    const int bbase = (bn0 >> 7) << 7;       // b * 128
    const int tid   = threadIdx.x;
    const int w     = tid >> 6;
    const int lane  = tid & 63;
    const int lq    = lane >> 4;
    const int arow  = lane & 15;

    __shared__ __align__(16) unsigned short HhP[2][8 * 64 * 8];  // 16384 B
    __shared__ __align__(16) unsigned short HlP[2][8 * 64 * 8];  // 16384 B
    __shared__ float scut[2][Kk];
    __shared__ int   snbr[2][Kk];

    if (tid < 96) {
        const int a = tid / 48, k = tid - (tid / 48) * 48;
        scut[a][k] = fcut[(bn0 + a) * Kk + k];
        snbr[a][k] = nbr[(bn0 + a) * Kk + k];
    }

    const float b1v  = b1[w * 32 + arow];
    const float b1v2 = b1[w * 32 + 16 + arow];
    const float b2v0 = b2[w * 32 + arow];
    const float b2v1 = b2[w * 32 + 16 + arow];

    float aggp[2][2] = {{0.f, 0.f}, {0.f, 0.f}};

    #pragma unroll 1
    for (int mt = 0; mt < 3; ++mt) {
        // ============ layer 1 (MFMA) for both atoms -> H-tile to LDS ========
        #pragma unroll
        for (int a = 0; a < 2; ++a) {
            // preload fexp A-fragments (coalesced)
            bf16x8 fah[2], fal[2];
            #pragma unroll
            for (int kk = 0; kk < 2; ++kk) {
                const size_t off = (((size_t)(bn0 + a) * 6 + mt * 2 + kk) * 64 + lane) * 8;
                fah[kk] = *reinterpret_cast<const bf16x8*>(feh + off);
                fal[kk] = *reinterpret_cast<const bf16x8*>(fel + off);
            }

            f32x4 acc1[2];
            acc1[0] = (f32x4){0.f, 0.f, 0.f, 0.f};
            acc1[1] = (f32x4){0.f, 0.f, 0.f, 0.f};

            #pragma unroll
            for (int kk = 0; kk < 2; ++kk) {
                #pragma unroll
                for (int nt = 0; nt < 2; ++nt) {
                    const size_t off = ((size_t)((2 * w + nt) * 2 + kk) * 64 + lane) * 8;
                    bf16x8 bh = *reinterpret_cast<const bf16x8*>(w1hp + off);
                    bf16x8 bl = *reinterpret_cast<const bf16x8*>(w1lp + off);
                    acc1[nt] = MFMA_B16(fah[kk], bh, acc1[nt]);
                    acc1[nt] = MFMA_B16(fah[kk], bl, acc1[nt]);
                    acc1[nt] = MFMA_B16(fal[kk], bh, acc1[nt]);
                }
            }

            #pragma unroll
            for (int nt = 0; nt < 2; ++nt) {
                const float bb = nt ? b1v2 : b1v;
                const int a_ = (nt * 2 + (arow >> 3)) << 4;
                const int i_ = arow & 7;
                #pragma unroll
                for (int j = 0; j < 4; ++j) {
                    float v = ssp_f(acc1[nt][j] + bb);
                    unsigned short hh = f2bf(v);
                    unsigned short ll = f2bf(v - bf2f(hh));
                    const int fl = (lq * 4 + j) | a_;
                    const int idx = (w * 64 + fl) * 8 + i_;
                    HhP[a][idx] = hh;
                    HlP[a][idx] = ll;
                }
            }
        }
        __syncthreads();

        // ============ layer 2 (MFMA): B-frags shared across both atoms ======
        f32x4 acc2[2][2];
        #pragma unroll
        for (int a = 0; a < 2; ++a) {
            acc2[a][0] = (f32x4){0.f, 0.f, 0.f, 0.f};
            acc2[a][1] = (f32x4){0.f, 0.f, 0.f, 0.f};
        }

        #pragma unroll 1
        for (int kk = 0; kk < 8; ++kk) {
            bf16x8 bh[2], bl[2];
            #pragma unroll
            for (int nt = 0; nt < 2; ++nt) {
                const size_t off = ((size_t)((2 * w + nt) * 8 + kk) * 64 + lane) * 8;
                bh[nt] = *reinterpret_cast<const bf16x8*>(whp + off);
                bl[nt] = *reinterpret_cast<const bf16x8*>(wlp + off);
            }
            const int abase = (kk * 64 + lane) * 8;
            #pragma unroll
            for (int a = 0; a < 2; ++a) {
                bf16x8 ah = *reinterpret_cast<const bf16x8*>(&HhP[a][abase]);
                bf16x8 al = *reinterpret_cast<const bf16x8*>(&HlP[a][abase]);
                #pragma unroll
                for (int nt = 0; nt < 2; ++nt) {
                    acc2[a][nt] = MFMA_B16(ah, bh[nt], acc2[a][nt]);
                    acc2[a][nt] = MFMA_B16(ah, bl[nt], acc2[a][nt]);
                    acc2[a][nt] = MFMA_B16(al, bh[nt], acc2[a][nt]);
                }
            }
        }

        // ============ consume this m-tile ====================================
        #pragma unroll
        for (int a = 0; a < 2; ++a) {
            #pragma unroll
            for (int j = 0; j < 4; ++j) {
                const int r = mt * 16 + lq * 4 + j;
                const float ct = scut[a][r];
                const int   nb = snbr[a][r];
                const float* yr = y + (size_t)(bbase + nb) * Ff + w * 32 + arow;
                aggp[a][0] = fmaf((acc2[a][0][j] + b2v0) * ct, yr[0],  aggp[a][0]);
                aggp[a][1] = fmaf((acc2[a][1][j] + b2v1) * ct, yr[16], aggp[a][1]);
            }
        }
        __syncthreads();   // H-tile consumed; next mt may overwrite
    }

    // ---- reduce across lq, write agg for both atoms ----
    #pragma unroll
    for (int a = 0; a < 2; ++a) {
        #pragma unroll
        for (int nt = 0; nt < 2; ++nt) {
            aggp[a][nt] += __shfl_xor(aggp[a][nt], 16);
            aggp[a][nt] += __shfl_xor(aggp[a][nt], 32);
        }
        if (lq == 0) {
            agg[(size_t)(bn0 + a) * Ff + w * 32 + arow]      = aggp[a][0];
            agg[(size_t)(bn0 + a) * Ff + w * 32 + 16 + arow] = aggp[a][1];
        }
    }
}

// ---------------------------------------------------------------------------
// k_f2out: x += ssp(agg@fw1+fb1)@fw2+fb2, 8 atoms per block (VALU)
// ---------------------------------------------------------------------------
__global__ __launch_bounds__(256) void k_f2out(
    const float* __restrict__ agg,
    const float* __restrict__ fw1, const float* __restrict__ fb1,
    const float* __restrict__ fw2, const float* __restrict__ fb2,
    float* __restrict__ x)
{
    const int bn0 = blockIdx.x * 8;
    const int tid = threadIdx.x;
    const int tx  = tid & 63;
    const int ty  = tid >> 6;
    const int f4  = tx * 4;

    __shared__ __align__(16) float sin_[8][Ff];     // 8 KB (agg, then sv)
    __shared__ __align__(16) float part[4][8][Ff];  // 32 KB

    #pragma unroll
    for (int a = 0; a < 8; ++a)
        sin_[a][tid] = agg[(size_t)(bn0 + a) * Ff + tid];
    __syncthreads();

    {
        float p[8][4];
        #pragma unroll
        for (int a = 0; a < 8; ++a) { p[a][0] = 0.f; p[a][1] = 0.f; p[a][2] = 0.f; p[a][3] = 0.f; }
        #pragma unroll 1
        for (int c = 0; c < 8; ++c) {
            const int h0 = ty * 64 + c * 8;
            float4 wq[8];
            #pragma unroll
            for (int j = 0; j < 8; ++j)
                wq[j] = LDG4(&fw1[(h0 + j) * Ff + f4]);
            #pragma unroll
            for (int a = 0; a < 8; ++a) {
                const float4 a0 = LDG4(&sin_[a][h0]);
                const float4 a1 = LDG4(&sin_[a][h0 + 4]);
                FMA4(p[a], a0.x, wq[0]); FMA4(p[a], a0.y, wq[1]);
                FMA4(p[a], a0.z, wq[2]); FMA4(p[a], a0.w, wq[3]);
                FMA4(p[a], a1.x, wq[4]); FMA4(p[a], a1.y, wq[5]);
                FMA4(p[a], a1.z, wq[6]); FMA4(p[a], a1.w, wq[7]);
            }
        }
        #pragma unroll
        for (int a = 0; a < 8; ++a)
            ST4(&part[ty][a][f4], make_float4(p[a][0], p[a][1], p[a][2], p[a][3]));
    }
    __syncthreads();
    {
        const float fb = fb1[tid];
        #pragma unroll
        for (int a = 0; a < 8; ++a) {
            float u = part[0][a][tid] + part[1][a][tid]
                    + part[2][a][tid] + part[3][a][tid] + fb;
            sin_[a][tid] = ssp_f(u);
        }
    }
    __syncthreads();

    {
        float p[8][4];
        #pragma unroll
        for (int a = 0; a < 8; ++a) { p[a][0] = 0.f; p[a][1] = 0.f; p[a][2] = 0.f; p[a][3] = 0.f; }
        #pragma unroll 1
        for (int c = 0; c < 8; ++c) {
            const int h0 = ty * 64 + c * 8;
            float4 wq[8];
            #pragma unroll
            for (int j = 0; j < 8; ++j)
                wq[j] = LDG4(&fw2[(h0 + j) * Ff + f4]);
            #pragma unroll
            for (int a = 0; a < 8; ++a) {
                const float4 a0 = LDG4(&sin_[a][h0]);
                const float4 a1 = LDG4(&sin_[a][h0 + 4]);
                FMA4(p[a], a0.x, wq[0]); FMA4(p[a], a0.y, wq[1]);
                FMA4(p[a], a0.z, wq[2]); FMA4(p[a], a0.w, wq[3]);
                FMA4(p[a], a1.x, wq[4]); FMA4(p[a], a1.y, wq[5]);
                FMA4(p[a], a1.z, wq[6]); FMA4(p[a], a1.w, wq[7]);
            }
        }
        #pragma unroll
        for (int a = 0; a < 8; ++a)
            ST4(&part[ty][a][f4], make_float4(p[a][0], p[a][1], p[a][2], p[a][3]));
    }
    __syncthreads();
    {
        const float fb = fb2[tid];
        #pragma unroll
        for (int a = 0; a < 8; ++a) {
            float o = part[0][a][tid] + part[1][a][tid]
                    + part[2][a][tid] + part[3][a][tid] + fb;
            x[(size_t)(bn0 + a) * Ff + tid] += o;
        }
    }
}

// ---------------------------------------------------------------------------
// k_head: disp/frac/rep, predictor MLP, masked mean, new_cell, new_pos
// ---------------------------------------------------------------------------
__global__ __launch_bounds__(128) void k_head(
    const float* __restrict__ x, const float* __restrict__ pos,
    const float* __restrict__ cell, const float* __restrict__ amask,
    const float* __restrict__ fdw, const float* __restrict__ fdb,
    const float* __restrict__ pw1, const float* __restrict__ pb1,
    const float* __restrict__ pw2, const float* __restrict__ pb2,
    float* __restrict__ out_pos, float* __restrict__ out_cell)
{
    const int b = blockIdx.x;
    const int n = threadIdx.x;

    __shared__ float sinv[9];
    __shared__ float scell[9];
    __shared__ float snc[9];
    __shared__ float sred[Nn][10];

    if (n == 0) {
        float c[9];
        #pragma unroll
        for (int i = 0; i < 9; ++i) { c[i] = cell[b * 9 + i]; scell[i] = c[i]; }
        float det = c[0] * (c[4] * c[8] - c[5] * c[7])
                  - c[1] * (c[3] * c[8] - c[5] * c[6])
                  + c[2] * (c[3] * c[7] - c[4] * c[6]);
        float id = 1.0f / det;
        sinv[0] = (c[4] * c[8] - c[5] * c[7]) * id;
        sinv[1] = (c[2] * c[7] - c[1] * c[8]) * id;
        sinv[2] = (c[1] * c[5] - c[2] * c[4]) * id;
        sinv[3] = (c[5] * c[6] - c[3] * c[8]) * id;
        sinv[4] = (c[0] * c[8] - c[2] * c[6]) * id;
        sinv[5] = (c[2] * c[3] - c[0] * c[5]) * id;
        sinv[6] = (c[3] * c[7] - c[4] * c[6]) * id;
        sinv[7] = (c[1] * c[6] - c[0] * c[7]) * id;
        sinv[8] = (c[0] * c[4] - c[1] * c[3]) * id;
    }
    __syncthreads();

    float xv0 = 0.f, xv1 = 0.f, xv2 = 0.f;
    const int row = (b * Nn + n) * Ff;
    for (int ff = 0; ff < Ff; ++ff) {
        float xr = x[row + ff];
        xv0 = fmaf(xr, fdw[ff * 3 + 0], xv0);
        xv1 = fmaf(xr, fdw[ff * 3 + 1], xv1);
        xv2 = fmaf(xr, fdw[ff * 3 + 2], xv2);
    }
    float fr[3];
    float dsp[3] = {xv0, xv1, xv2};
    const float p0 = pos[(b * Nn + n) * 3 + 0];
    const float p1 = pos[(b * Nn + n) * 3 + 1];
    const float p2 = pos[(b * Nn + n) * 3 + 2];
    #pragma unroll
    for (int j = 0; j < 3; ++j) {
        float z = 10.0f * (dsp[j] + fdb[j]);
        float s = 1.0f / (1.0f + expf(-z));
        float fx = p0 * sinv[0 * 3 + j] + p1 * sinv[1 * 3 + j] + p2 * sinv[2 * 3 + j] + s;
        fr[j] = fx - floorf(fx);
    }

    float rep[3];
    #pragma unroll
    for (int j = 0; j < 3; ++j)
        rep[j] = fr[0] * scell[0 * 3 + j] + fr[1] * scell[1 * 3 + j] + fr[2] * scell[2 * 3 + j];

    float a6[6];
    #pragma unroll
    for (int i = 0; i < 6; ++i) {
        float uv = rep[0] * pw1[0 * 6 + i] + rep[1] * pw1[1 * 6 + i]
                 + rep[2] * pw1[2 * 6 + i] + pb1[i];
        a6[i] = ssp_f(uv);
    }
    float h9[9];
    #pragma unroll
    for (int o = 0; o < 9; ++o) {
        float uv = pb2[o];
        #pragma unroll
        for (int i = 0; i < 6; ++i) uv = fmaf(a6[i], pw2[i * 9 + o], uv);
        h9[o] = uv;
    }

    const float m = amask[b * Nn + n];
    #pragma unroll
    for (int o = 0; o < 9; ++o) sred[n][o] = h9[o] * m;
    sred[n][9] = m;
    __syncthreads();

    for (int s = 64; s >= 1; s >>= 1) {
        if (n < s) {
            #pragma unroll
            for (int o = 0; o < 10; ++o) sred[n][o] += sred[n + s][o];
        }
        __syncthreads();
    }

    if (n < 9) {
        float na = sred[0][9];
        float yo = sred[0][n] / na;
        float scale = 3.0f * powf(na, 1.0f / 3.0f);
        int r = n / 3, c = n - r * 3;
        float v = scale * (((r == c) ? 1.0f : 0.0f) + yo);
        snc[n] = v;
        out_cell[b * 9 + n] = v;
    }
    __syncthreads();

    #pragma unroll
    for (int j = 0; j < 3; ++j) {
        float v = fr[0] * snc[0 * 3 + j] + fr[1] * snc[1 * 3 + j] + fr[2] * snc[2 * 3 + j];
        out_pos[(b * Nn + n) * 3 + j] = v;
    }
}

// ---------------------------------------------------------------------------
extern "C" void kernel_launch(void* const* d_in, const int* in_sizes, int n_in,
                              void* d_out, int out_size, void* d_ws, size_t ws_size,
                              hipStream_t stream)
{
    const float* positions     = (const float*)d_in[0];
    const float* cell          = (const float*)d_in[1];
    const int*   atomic_nums   = (const int*)  d_in[2];
    const int*   neighbors     = (const int*)  d_in[3];
    const float* neighbor_mask = (const float*)d_in[4];
    const float* atom_mask     = (const float*)d_in[5];
    const float* embedding     = (const float*)d_in[6];
    const float* filt_w1       = (const float*)d_in[7];
    const float* filt_b1       = (const float*)d_in[8];
    const float* filt_w2       = (const float*)d_in[9];
    const float* filt_b2       = (const float*)d_in[10];
    const float* in2f_w        = (const float*)d_in[11];
    const float* f2out_w1      = (const float*)d_in[12];
    const float* f2out_b1      = (const float*)d_in[13];
    const float* f2out_w2      = (const float*)d_in[14];
    const float* f2out_b2      = (const float*)d_in[15];
    const float* fd_w          = (const float*)d_in[16];
    const float* fd_b          = (const float*)d_in[17];
    const float* pred_w1       = (const float*)d_in[18];
    const float* pred_b1       = (const float*)d_in[19];
    const float* pred_w2       = (const float*)d_in[20];
    const float* pred_b2       = (const float*)d_in[21];

    float* ws   = (float*)d_ws;
    float* x    = ws;                          // 1048576 f32
    float* y    = x + Bb * Nn * Ff;            // 1048576 f32
    float* agg  = y + Bb * Nn * Ff;            // 1048576 f32
    float* sd   = agg + Bb * Nn * Ff;          // 196608 f32
    float* fcut = sd + Bb * Nn * Kk;           // 196608 f32
    unsigned short* whp  = (unsigned short*)(fcut + Bb * Nn * Kk);
    unsigned short* wlp  = whp + (size_t)Tt * Ff * Ff;
    unsigned short* ihp  = wlp + (size_t)Tt * Ff * Ff;
    unsigned short* ilp  = ihp + (size_t)Tt * Ff * Ff;
    unsigned short* w1hp = ilp + (size_t)Tt * Ff * Ff;
    unsigned short* w1lp = w1hp + (size_t)Tt * Ff * 64;
    unsigned short* feh  = w1lp + (size_t)Tt * Ff * 64;   // BN*6*64*8
    unsigned short* fel  = feh + (size_t)Bb * Nn * 6 * 64 * 8;

    float* out_pos  = (float*)d_out;
    float* out_cell = out_pos + Bb * Nn * 3;

    const int BN = Bb * Nn;

    k_setup<<<BN, 256, 0, stream>>>(positions, atomic_nums, neighbors,
                                    neighbor_mask, embedding, x, sd, fcut);
    k_packfe<<<BN, 384, 0, stream>>>(sd, feh, fel);
    k_pack256<<<Tt * 128, 64, 0, stream>>>(filt_w2, whp, wlp);
    k_pack256<<<Tt * 128, 64, 0, stream>>>(in2f_w, ihp, ilp);
    k_pack64<<<Tt * 32, 64, 0, stream>>>(filt_w1, w1hp, w1lp);

    for (int t = 0; t < Tt; ++t) {
        k_y16m<<<BN / 16, 512, 0, stream>>>(x,
                                            ihp + (size_t)t * Ff * Ff,
                                            ilp + (size_t)t * Ff * Ff,
                                            y);
        k_aggm4b<<<BN / 2, 512, 0, stream>>>(fcut, neighbors, y,
                                             feh, fel,
                                             w1hp + (size_t)t * Ff * 64,
                                             w1lp + (size_t)t * Ff * 64,
                                             filt_b1 + (size_t)t * Ff,
                                             whp + (size_t)t * Ff * Ff,
                                             wlp + (size_t)t * Ff * Ff,
                                             filt_b2 + (size_t)t * Ff,
                                             agg);
        k_f2out<<<BN / 8, 256, 0, stream>>>(agg,
                                            f2out_w1 + (size_t)t * Ff * Ff,
                                            f2out_b1 + (size_t)t * Ff,
                                            f2out_w2 + (size_t)t * Ff * Ff,
                                            f2out_b2 + (size_t)t * Ff,
                                            x);
    }

    k_head<<<Bb, 128, 0, stream>>>(x, positions, cell, atom_mask,
                                   fd_w, fd_b, pred_w1, pred_b1, pred_w2, pred_b2,
                                   out_pos, out_cell);
}